// Round 6
// baseline (277.659 us; speedup 1.0000x reference)
//
#include <hip/hip_runtime.h>
#include <hip/hip_bf16.h>
#include <stdint.h>

#define B_ 4
#define S_ 2048
#define DM_ 768
#define H_ 12
#define HD_ 64
#define ROWS (B_*S_)      // 8192
#define QKVN (3*DM_)      // 2304

typedef __attribute__((ext_vector_type(8))) short short8;
typedef __attribute__((ext_vector_type(4))) float floatx4;
typedef __attribute__((ext_vector_type(8))) unsigned short ushort8;
typedef __attribute__((ext_vector_type(4))) unsigned short ushort4v;
typedef __attribute__((ext_vector_type(4))) float float4_t;

__device__ __forceinline__ unsigned short f2b(float f) {
  union { float f; uint32_t u; } x; x.f = f;
  uint32_t r = x.u + 0x7FFFu + ((x.u >> 16) & 1u);
  return (unsigned short)(r >> 16);
}
__device__ __forceinline__ float b2f(unsigned short u) {
  union { uint32_t u; float f; } x; x.u = ((uint32_t)u) << 16; return x.f;
}
__device__ __forceinline__ uint32_t fbits(float f) {
  union { float f; uint32_t u; } x; x.f = f; return x.u;
}

// async global->LDS, 16B per lane. LDS dest is wave-uniform base + lane*16.
__device__ __forceinline__ void load_lds16(const void* g, void* l) {
  __builtin_amdgcn_global_load_lds(
      (const __attribute__((address_space(1))) uint32_t*)g,
      (__attribute__((address_space(3))) uint32_t*)l, 16, 0, 0);
}

// ---------------- fused prep: base cast + 3 weight transposes + norm-fusion aux ----------
// block ranges: [0,6144) cvt | [6144,7872) Wqkv | [7872,8448) W1 | [8448,9024) W2
//               [9024,9088) zero rs1/rq1 | [9088,9091) colsum(W2)
#define CVT_B 6144
#define WQ_B 1728
#define W1_B 576
#define PREP_B (CVT_B + WQ_B + 2 * W1_B + 64 + 3)
__global__ __launch_bounds__(256) void prep(
    const float* __restrict__ base, unsigned short* __restrict__ base_bf,
    const float* __restrict__ Wqkv, unsigned short* __restrict__ Wqkvt,
    const float* __restrict__ W1, unsigned short* __restrict__ W1t,
    const float* __restrict__ W2, unsigned short* __restrict__ W2t,
    float* __restrict__ rs1, float* __restrict__ rq1, float* __restrict__ cs2) {
  __shared__ float t[32][33];
  int bid = blockIdx.x;
  int tid = threadIdx.x;
  if (bid < CVT_B) {
    int i = bid * 256 + tid;
    float4_t v = ((const float4_t*)base)[i];
    ushort4v o;
    o[0] = f2b(v[0]); o[1] = f2b(v[1]); o[2] = f2b(v[2]); o[3] = f2b(v[3]);
    ((ushort4v*)base_bf)[i] = o;
    return;
  }
  if (bid >= CVT_B + WQ_B + 2 * W1_B) {
    int r2 = bid - (CVT_B + WQ_B + 2 * W1_B);
    if (r2 < 64) {  // zero row-stat accumulators (16384 floats)
      int i = r2 * 256 + tid;
      if (i < ROWS) rs1[i] = 0.0f; else rq1[i - ROWS] = 0.0f;
      return;
    }
    int col = (r2 - 64) * 256 + tid;  // 0..767: cs2[col] = sum_k W2[k][col]
    float s = 0.0f;
    for (int k = 0; k < DM_; k++) s += W2[(size_t)k * DM_ + col];
    cs2[col] = s;
    return;
  }
  const float* W; unsigned short* Wt; int N, rel;
  if (bid < CVT_B + WQ_B)      { W = Wqkv; Wt = Wqkvt; N = QKVN; rel = bid - CVT_B; }
  else if (bid < CVT_B + WQ_B + W1_B) { W = W1; Wt = W1t; N = DM_; rel = bid - CVT_B - WQ_B; }
  else                          { W = W2; Wt = W2t; N = DM_; rel = bid - CVT_B - WQ_B - W1_B; }
  int K = DM_;
  int n0 = (rel % (N / 32)) * 32, k0 = (rel / (N / 32)) * 32;
  int tx = tid & 31, ty = tid >> 5;  // ty 0..7
#pragma unroll
  for (int i = 0; i < 4; i++)
    t[ty + i * 8][tx] = W[(size_t)(k0 + ty + i * 8) * N + n0 + tx];
  __syncthreads();
#pragma unroll
  for (int i = 0; i < 4; i++)
    Wt[(size_t)(n0 + ty + i * 8) * K + k0 + tx] = f2b(t[tx][ty + i * 8]);
}

// ---------------- bf16 MFMA GEMM (128x128 tile, BK=128): QKV + fused V-transpose ----------
// XOR-swizzled LDS (16 chunks/row). Q cols pre-scaled by 0.125*log2(e).
// R3: 1D XCD-swizzled grid (each XCD owns 8 m x 18 n, m-fastest: A-panels L2-resident).
// R6: Q/K epilogue vectorized via per-wave LDS scratch (scalar b16 LDS writes, 2-way
//     conflicts = free; then b128 reads + dwordx4 global stores, fully coalesced).
__global__ __launch_bounds__(256, 2) void gemm_qkv(
    const unsigned short* __restrict__ A,
    const unsigned short* __restrict__ Bt,
    const float* __restrict__ bias,
    unsigned short* __restrict__ Cout,
    unsigned short* __restrict__ Vt,
    int M, int N, int K) {
  __shared__ __align__(16) unsigned short LDSbuf[2 * 128 * 128];  // As | Bs (64 KB)
  unsigned short* As = LDSbuf;
  unsigned short* Bs = LDSbuf + 128 * 128;
  int tid = threadIdx.x;
  int wave = tid >> 6, lane = tid & 63;
  int quad = lane >> 4, l16 = lane & 15;
  int sr4 = lane >> 4;                // staging row within 4-row op
  int c16 = lane & 15;                // staging chunk position
  int flat = blockIdx.x;              // 0..1151
  int xcd = flat & 7, widx = flat >> 3;          // widx 0..143
  int mb = xcd * 8 + (widx & 7);                 // 0..63
  int nb = widx >> 3;                            // 0..17
  int m0 = mb * 128, n0 = nb * 128;
  int wm = (wave >> 1) * 64, wn = (wave & 1) * 64;
  floatx4 acc[4][4] = {};

  for (int kb = 0; kb < K; kb += 128) {
#pragma unroll
    for (int i = 0; i < 8; i++) {
      int op = wave * 8 + i;
      int srow = op * 4 + sr4;
      int sc = c16 ^ (srow & 15);
      load_lds16(A + (size_t)(m0 + srow) * K + kb + sc * 8, (char*)As + op * 1024);
    }
#pragma unroll
    for (int i = 0; i < 8; i++) {
      int op = wave * 8 + i;
      int srow = op * 4 + sr4;
      int sc = c16 ^ (srow & 15);
      load_lds16(Bt + (size_t)(n0 + srow) * K + kb + sc * 8, (char*)Bs + op * 1024);
    }
    __syncthreads();  // drains vmcnt + barrier
#pragma unroll
    for (int ks = 0; ks < 4; ks++) {
      short8 af[4], bfr[4];
#pragma unroll
      for (int mt = 0; mt < 4; mt++)
        af[mt] = *(const short8*)(As + (wm + mt * 16 + l16) * 128 + ((ks * 4 + quad) ^ l16) * 8);
#pragma unroll
      for (int nt = 0; nt < 4; nt++)
        bfr[nt] = *(const short8*)(Bs + (wn + nt * 16 + l16) * 128 + ((ks * 4 + quad) ^ l16) * 8);
#pragma unroll
      for (int mt = 0; mt < 4; mt++)
#pragma unroll
        for (int nt = 0; nt < 4; nt++)
          acc[mt][nt] = __builtin_amdgcn_mfma_f32_16x16x32_bf16(af[mt], bfr[nt], acc[mt][nt], 0, 0, 0);
    }
    __syncthreads();  // also guarantees all ds_reads done before epilogue LDS reuse
  }

  unsigned short* scr = LDSbuf + wave * 4608;  // per-wave scratch, row stride 72 ushorts
  if (n0 < 2 * DM_) {
    // Q/K epilogue: assemble wave's 64x64 bf16 tile in scratch, store vectorized
    float qs = (n0 < DM_) ? 0.18033688011112042f : 1.0f;  // 0.125*log2(e) pre-scales Q
#pragma unroll
    for (int nt = 0; nt < 4; nt++) {
      float bv = bias[n0 + wn + nt * 16 + l16];
#pragma unroll
      for (int mt = 0; mt < 4; mt++)
#pragma unroll
        for (int r = 0; r < 4; r++)
          scr[(mt * 16 + quad * 4 + r) * 72 + nt * 16 + l16] = f2b((acc[mt][nt][r] + bv) * qs);
    }
#pragma unroll
    for (int it = 0; it < 8; it++) {
      int row = it * 8 + (lane >> 3);
      int ch = lane & 7;
      ushort8 w = *(const ushort8*)(scr + row * 72 + ch * 8);
      *(ushort8*)(Cout + (size_t)(m0 + wm + row) * N + n0 + wn + ch * 8) = w;
    }
  } else {
    // V epilogue: transpose + key-permute into Vt[(b*H+h)*64 + d][s]
    int h = (n0 + wn - 2 * DM_) >> 6;
    int b = m0 >> 11;
    int s_base = (m0 & (S_ - 1)) + wm;
#pragma unroll
    for (int nt = 0; nt < 4; nt++) {
      float bv = bias[n0 + wn + nt * 16 + l16];
      ushort8 v0, v1;
#pragma unroll
      for (int j = 0; j < 8; j++) {
        v0[j] = f2b(acc[j & 3][nt][j >> 2] + bv);
        v1[j] = f2b(acc[j & 3][nt][2 + (j >> 2)] + bv);
      }
      // pos = 16*quad + 4r + mt holds acc[mt][nt][r]  (perm(s)= (s&15)*4+(s>>4))
      *(ushort8*)(scr + (nt * 16 + l16) * 72 + quad * 16) = v0;
      *(ushort8*)(scr + (nt * 16 + l16) * 72 + quad * 16 + 8) = v1;
    }
#pragma unroll
    for (int it = 0; it < 8; it++) {
      int d = it * 8 + (lane >> 3);
      int ch = lane & 7;
      ushort8 w = *(const ushort8*)(scr + d * 72 + ch * 8);
      *(ushort8*)(Vt + ((size_t)(b * H_ + h) * 64 + d) * S_ + s_base + ch * 8) = w;
    }
  }
}

// ---------------- bf16 MFMA GEMM (64x128 tile, 4 blocks/CU): MLP GEMMs ----------------
// R3: 1D XCD-swizzled grid (each XCD owns 16 m x 6 n, m-fastest).
// R6 norm fusion:
//  EPI=1 (t1 = av@W1+b1+base): writes bf16 t1; atomically accumulates per-row
//         sum/sumsq of the ROUNDED values into rs/rq (norm1 stats).
//  EPI=2 (out2 = relu(hidden@W2+b2)+hidden, hidden=norm1(t1)=a*t1+c):
//         uses (a*t1+c)@W2 = a*(t1@W2) + c*colsum(W2); res=t1 re-affined for the
//         residual. normk<1> kernel + hbf round trip eliminated.
template <int EPI>
__global__ __launch_bounds__(256, 4) void gemm64(
    const unsigned short* __restrict__ A,
    const unsigned short* __restrict__ Bt,
    const float* __restrict__ bias,
    const unsigned short* __restrict__ res,
    unsigned short* __restrict__ Cout,
    float* __restrict__ rs, float* __restrict__ rq,
    const float* __restrict__ cs2,
    const float* __restrict__ nsc, const float* __restrict__ nbi,
    int M, int N, int K) {
  __shared__ __align__(16) unsigned short As[64 * 64];
  __shared__ __align__(16) unsigned short Bs[128 * 64];
  int tid = threadIdx.x;
  int wave = tid >> 6, lane = tid & 63;
  int quad = lane >> 4, l16 = lane & 15;
  int e = l16 & 7;
  int sr = lane >> 3;
  int sc = (lane & 7) ^ (sr & 7);
  int flat = blockIdx.x;              // 0..767
  int xcd = flat & 7, widx = flat >> 3;          // widx 0..95
  int mb = xcd * 16 + (widx & 15);               // 0..127
  int nb = widx >> 4;                            // 0..5
  int m0 = mb * 64, n0 = nb * 128;
  int wm = (wave >> 1) * 32, wn = (wave & 1) * 64;
  floatx4 acc[2][4] = {};

  for (int kb = 0; kb < K; kb += 64) {
#pragma unroll
    for (int i = 0; i < 2; i++) {
      int op = wave * 2 + i;  // 8 A ops
      load_lds16(A + (size_t)(m0 + op * 8 + sr) * K + kb + sc * 8, (char*)As + op * 1024);
    }
#pragma unroll
    for (int i = 0; i < 4; i++) {
      int op = wave * 4 + i;  // 16 B ops
      load_lds16(Bt + (size_t)(n0 + op * 8 + sr) * K + kb + sc * 8, (char*)Bs + op * 1024);
    }
    __syncthreads();
#pragma unroll
    for (int ks = 0; ks < 2; ks++) {
      short8 af[2], bfr[4];
#pragma unroll
      for (int mt = 0; mt < 2; mt++)
        af[mt] = *(const short8*)(As + (wm + mt * 16 + l16) * 64 + ((ks * 4 + quad) ^ e) * 8);
#pragma unroll
      for (int nt = 0; nt < 4; nt++)
        bfr[nt] = *(const short8*)(Bs + (wn + nt * 16 + l16) * 64 + ((ks * 4 + quad) ^ e) * 8);
#pragma unroll
      for (int mt = 0; mt < 2; mt++)
#pragma unroll
        for (int nt = 0; nt < 4; nt++)
          acc[mt][nt] = __builtin_amdgcn_mfma_f32_16x16x32_bf16(af[mt], bfr[nt], acc[mt][nt], 0, 0, 0);
    }
    __syncthreads();
  }
  const float inv768 = 1.0f / (float)DM_;
  if (EPI == 1) {
#pragma unroll
    for (int mt = 0; mt < 2; mt++) {
#pragma unroll
      for (int r = 0; r < 4; r++) {
        float srow = 0.0f, qrow = 0.0f;
        int row = m0 + wm + mt * 16 + quad * 4 + r;
#pragma unroll
        for (int nt = 0; nt < 4; nt++) {
          int col = n0 + wn + nt * 16 + l16;
          size_t idx = (size_t)row * N + col;
          float v = acc[mt][nt][r] + bias[col] + b2f(res[idx]);
          unsigned short vb = f2b(v);
          Cout[idx] = vb;
          float vr = b2f(vb);
          srow += vr; qrow += vr * vr;
        }
#pragma unroll
        for (int o = 1; o < 16; o <<= 1) {
          srow += __shfl_xor(srow, o);
          qrow += __shfl_xor(qrow, o);
        }
        if (l16 == 0) {
          atomicAdd(&rs[row], srow);
          atomicAdd(&rq[row], qrow);
        }
      }
    }
  } else {
    float sg = nsc[0], bg = nbi[0];
#pragma unroll
    for (int mt = 0; mt < 2; mt++) {
#pragma unroll
      for (int r = 0; r < 4; r++) {
        int row = m0 + wm + mt * 16 + quad * 4 + r;
        float mean = rs[row] * inv768;
        float a = rsqrtf(rq[row] * inv768 - mean * mean) * sg;
        float c = bg - mean * a;
#pragma unroll
        for (int nt = 0; nt < 4; nt++) {
          int col = n0 + wn + nt * 16 + l16;
          size_t idx = (size_t)row * N + col;
          float g = a * acc[mt][nt][r] + c * cs2[col] + bias[col];
          g = fmaxf(g, 0.0f);
          float hid = a * b2f(res[idx]) + c;
          Cout[idx] = f2b(g + hid);
        }
      }
    }
  }
}

// ---------------- flash attention: av = softmax(Q K^T / 8) V ----------------
// (R5 form, at its structural latency floor ~65us: every pipe <=40%, residency
//  pinned at ~2 blocks/CU across 32-50KB LDS variants. Untouched this round.)
__global__ __launch_bounds__(256, 3) void attn(
    const unsigned short* __restrict__ qkv,
    const unsigned short* __restrict__ Vt,
    unsigned short* __restrict__ av) {
  int flat = blockIdx.x;                  // 0..767
  int widx = (flat & 7) * 96 + (flat >> 3);
  int qt = widx & 15;    // q-tile 0..15 (128 rows)
  int bh = widx >> 4;    // 0..47
  int b = bh / H_, h = bh % H_;
  int row0 = b * S_ + qt * 128;
  __shared__ __align__(16) unsigned short Ks[2][64 * 64];
  __shared__ __align__(16) unsigned short Vs[2][64 * 64];
  __shared__ __align__(16) unsigned short Ps[4][32 * 72];  // row stride 144B; doubles as Q staging
  int tid = threadIdx.x;
  int wave = tid >> 6, lane = tid & 63;
  int quad = lane >> 4, l16 = lane & 15;
  int e = l16 & 7;
  int sr = lane >> 3;
  int sc = (lane & 7) ^ (sr & 7);

#pragma unroll
  for (int i = 0; i < 4; i++) {
    load_lds16(qkv + (size_t)(row0 + wave * 32 + i * 8 + sr) * QKVN + h * HD_ + sc * 8,
               (char*)Ps[wave] + i * 1024);
  }
  const unsigned short* kp = qkv + (size_t)(b * S_ + wave * 16 + sr) * QKVN + DM_ + h * HD_ + sc * 8;
  const unsigned short* vp = Vt + ((size_t)bh * 64 + wave * 16 + sr) * S_ + sc * 8;
  auto stageKV = [&](const unsigned short* kq, const unsigned short* vq, int buf) {
#pragma unroll
    for (int i = 0; i < 2; i++) {
      load_lds16(kq + (size_t)i * 8 * QKVN, (char*)Ks[buf] + wave * 2048 + i * 1024);
      load_lds16(vq + (size_t)i * 8 * S_, (char*)Vs[buf] + wave * 2048 + i * 1024);
    }
  };
  stageKV(kp, vp, 0);

  floatx4 accO[2][4] = {};
  floatx4 accL[2] = {};
  short8 ones;
#pragma unroll
  for (int j = 0; j < 8; j++) ones[j] = (short)0x3F80;  // bf16 1.0
  __syncthreads();  // Q + KV(0) staged (drains vmcnt)

  short8 qf[2][2];
#pragma unroll
  for (int mf = 0; mf < 2; mf++)
#pragma unroll
    for (int ks = 0; ks < 2; ks++)
      qf[mf][ks] = *(const short8*)(Ps[wave] + (mf * 16 + l16) * 64 + ((ks * 4 + quad) ^ e) * 8);

  int cur = 0;
  for (int kt = 0; kt < 32; kt++) {
    if (kt + 1 < 32) {
      kp += 64 * QKVN;
      vp += 64;
      stageKV(kp, vp, cur ^ 1);
    }
    floatx4 sv[2][4] = {};
    __builtin_amdgcn_s_setprio(1);
#pragma unroll
    for (int ks = 0; ks < 2; ks++)
#pragma unroll
      for (int nt = 0; nt < 4; nt++) {
        short8 kf = *(const short8*)(Ks[cur] + (nt * 16 + l16) * 64 + ((ks * 4 + quad) ^ e) * 8);
#pragma unroll
        for (int mf = 0; mf < 2; mf++)
          sv[mf][nt] = __builtin_amdgcn_mfma_f32_16x16x32_bf16(qf[mf][ks], kf, sv[mf][nt], 0, 0, 0);
      }
    __builtin_amdgcn_s_setprio(0);
#pragma unroll
    for (int mf = 0; mf < 2; mf++)
#pragma unroll
      for (int r = 0; r < 4; r++) {
        uint32_t u0 = fbits(__builtin_amdgcn_exp2f(sv[mf][0][r]));
        uint32_t u1 = fbits(__builtin_amdgcn_exp2f(sv[mf][1][r]));
        uint32_t u2 = fbits(__builtin_amdgcn_exp2f(sv[mf][2][r]));
        uint32_t u3 = fbits(__builtin_amdgcn_exp2f(sv[mf][3][r]));
        uint2 val;
        val.x = __builtin_amdgcn_perm(u1, u0, 0x07060302u);  // [u0.hi16, u1.hi16]
        val.y = __builtin_amdgcn_perm(u3, u2, 0x07060302u);  // [u2.hi16, u3.hi16]
        *(uint2*)(&Ps[wave][(mf * 16 + quad * 4 + r) * 72 + l16 * 4]) = val;
      }
    __builtin_amdgcn_s_setprio(1);
#pragma unroll
    for (int ks = 0; ks < 2; ks++) {
      short8 pf[2];
#pragma unroll
      for (int mf = 0; mf < 2; mf++) {
        pf[mf] = *(const short8*)(Ps[wave] + (mf * 16 + l16) * 72 + ks * 32 + quad * 8);
        accL[mf] = __builtin_amdgcn_mfma_f32_16x16x32_bf16(pf[mf], ones, accL[mf], 0, 0, 0);
      }
#pragma unroll
      for (int nt = 0; nt < 4; nt++) {
        short8 vf = *(const short8*)(Vs[cur] + (nt * 16 + l16) * 64 + ((ks * 4 + quad) ^ e) * 8);
#pragma unroll
        for (int mf = 0; mf < 2; mf++)
          accO[mf][nt] = __builtin_amdgcn_mfma_f32_16x16x32_bf16(pf[mf], vf, accO[mf][nt], 0, 0, 0);
      }
    }
    __builtin_amdgcn_s_setprio(0);
    __syncthreads();  // drains prefetch vmcnt; all waves done with cur
    cur ^= 1;
  }
#pragma unroll
  for (int mf = 0; mf < 2; mf++)
#pragma unroll
    for (int r = 0; r < 4; r++) {
      float inv = 1.0f / accL[mf][r];
      int row = row0 + wave * 32 + mf * 16 + quad * 4 + r;
#pragma unroll
      for (int nt = 0; nt < 4; nt++)
        av[(size_t)row * DM_ + h * HD_ + nt * 16 + l16] = f2b(accO[mf][nt][r] * inv);
    }
}

// ---------------- row norm: (x-mean)/std * scale + bias (bf16 input) ----------------
// WB=1: write bf16 only. WB=0: write f32 only (final output).
template <int WB>
__global__ __launch_bounds__(256) void normk(
    const unsigned short* __restrict__ X, const float* __restrict__ scale,
    const float* __restrict__ bias, float* __restrict__ Y,
    unsigned short* __restrict__ Ybf) {
  int row = blockIdx.x;
  const unsigned short* x = X + (size_t)row * DM_;
  int tid = threadIdx.x;
  int wave = tid >> 6, lane = tid & 63;
  float v[3];
#pragma unroll
  for (int i = 0; i < 3; i++) v[i] = b2f(x[tid + i * 256]);
  float s = v[0] + v[1] + v[2];
#pragma unroll
  for (int o = 32; o > 0; o >>= 1) s += __shfl_xor(s, o);
  __shared__ float red[4];
  if (lane == 0) red[wave] = s;
  __syncthreads();
  float mean = (red[0] + red[1] + red[2] + red[3]) * (1.0f / DM_);
  float ss = 0.0f;
#pragma unroll
  for (int i = 0; i < 3; i++) { v[i] -= mean; ss += v[i] * v[i]; }
#pragma unroll
  for (int o = 32; o > 0; o >>= 1) ss += __shfl_xor(ss, o);
  __syncthreads();
  if (lane == 0) red[wave] = ss;
  __syncthreads();
  float var = (red[0] + red[1] + red[2] + red[3]) * (1.0f / DM_);
  float rstd = rsqrtf(var);
  float sg = scale[0], bg = bias[0];
#pragma unroll
  for (int i = 0; i < 3; i++) {
    float y = v[i] * rstd * sg + bg;
    if (WB) Ybf[(size_t)row * DM_ + tid + i * 256] = f2b(y);
    else    Y[(size_t)row * DM_ + tid + i * 256] = y;
  }
}

extern "C" void kernel_launch(void* const* d_in, const int* in_sizes, int n_in,
                              void* d_out, int out_size, void* d_ws, size_t ws_size,
                              hipStream_t stream) {
  const float* base = (const float*)d_in[0];
  const float* Wqkv = (const float*)d_in[1];
  const float* bqkv = (const float*)d_in[2];
  const float* W1 = (const float*)d_in[3];
  const float* b1 = (const float*)d_in[4];
  const float* W2 = (const float*)d_in[5];
  const float* b2 = (const float*)d_in[6];
  const float* n1s = (const float*)d_in[7];
  const float* n1b = (const float*)d_in[8];
  const float* n2s = (const float*)d_in[9];
  const float* n2b = (const float*)d_in[10];
  float* out = (float*)d_out;

  char* ws = (char*)d_ws;
  size_t off = 0;
  auto alloc = [&](size_t bytes) {
    char* p = ws + off;
    off = (off + bytes + 255) & ~(size_t)255;
    return p;
  };
  unsigned short* base_bf = (unsigned short*)alloc((size_t)ROWS * DM_ * 2);
  unsigned short* Wqkvt = (unsigned short*)alloc((size_t)QKVN * DM_ * 2);
  unsigned short* W1t = (unsigned short*)alloc((size_t)DM_ * DM_ * 2);
  unsigned short* W2t = (unsigned short*)alloc((size_t)DM_ * DM_ * 2);
  unsigned short* qkvb = (unsigned short*)alloc((size_t)ROWS * QKVN * 2);
  unsigned short* Vtb = (unsigned short*)alloc((size_t)B_ * H_ * HD_ * S_ * 2);
  unsigned short* avb = (unsigned short*)alloc((size_t)ROWS * DM_ * 2);
  unsigned short* t1b = (unsigned short*)alloc((size_t)ROWS * DM_ * 2);
  unsigned short* hbf = (unsigned short*)alloc((size_t)ROWS * DM_ * 2);  // gemm64<2> output
  float* rs1 = (float*)alloc((size_t)ROWS * 4);
  float* rq1 = (float*)alloc((size_t)ROWS * 4);
  float* cs2 = (float*)alloc((size_t)DM_ * 4);

  prep<<<PREP_B, 256, 0, stream>>>(
      base, base_bf, Wqkv, Wqkvt, W1, W1t, W2, W2t, rs1, rq1, cs2);
  gemm_qkv<<<dim3((QKVN / 128) * (ROWS / 128)), 256, 0, stream>>>(
      base_bf, Wqkvt, bqkv, qkvb, Vtb, ROWS, QKVN, DM_);
  attn<<<dim3((S_ / 128) * (B_ * H_)), 256, 0, stream>>>(qkvb, Vtb, avb);  // 768 blocks
  gemm64<1><<<dim3((DM_ / 128) * (ROWS / 64)), 256, 0, stream>>>(
      avb, W1t, b1, base_bf, t1b, rs1, rq1, nullptr, nullptr, nullptr, ROWS, DM_, DM_);
  gemm64<2><<<dim3((DM_ / 128) * (ROWS / 64)), 256, 0, stream>>>(
      t1b, W2t, b2, t1b, hbf, rs1, rq1, cs2, n1s, n1b, ROWS, DM_, DM_);
  normk<0><<<ROWS, 256, 0, stream>>>(hbf, n2s, n2b, out, nullptr);
}

// Round 7
// 258.430 us; speedup vs baseline: 1.0744x; 1.0744x over previous
//
#include <hip/hip_runtime.h>
#include <hip/hip_bf16.h>
#include <stdint.h>

#define B_ 4
#define S_ 2048
#define DM_ 768
#define H_ 12
#define HD_ 64
#define ROWS (B_*S_)      // 8192
#define QKVN (3*DM_)      // 2304

typedef __attribute__((ext_vector_type(8))) short short8;
typedef __attribute__((ext_vector_type(4))) float floatx4;
typedef __attribute__((ext_vector_type(8))) unsigned short ushort8;
typedef __attribute__((ext_vector_type(4))) unsigned short ushort4v;
typedef __attribute__((ext_vector_type(4))) float float4_t;

__device__ __forceinline__ unsigned short f2b(float f) {
  union { float f; uint32_t u; } x; x.f = f;
  uint32_t r = x.u + 0x7FFFu + ((x.u >> 16) & 1u);
  return (unsigned short)(r >> 16);
}
__device__ __forceinline__ float b2f(unsigned short u) {
  union { uint32_t u; float f; } x; x.u = ((uint32_t)u) << 16; return x.f;
}
__device__ __forceinline__ uint32_t fbits(float f) {
  union { float f; uint32_t u; } x; x.f = f; return x.u;
}

// async global->LDS, 16B per lane. LDS dest is wave-uniform base + lane*16.
__device__ __forceinline__ void load_lds16(const void* g, void* l) {
  __builtin_amdgcn_global_load_lds(
      (const __attribute__((address_space(1))) uint32_t*)g,
      (__attribute__((address_space(3))) uint32_t*)l, 16, 0, 0);
}

// ---------------- fused prep: base cast + 3 weight transposes + parallel colsum(W2) ------
// block ranges: [0,6144) cvt | [6144,7872) Wqkv | [7872,8448) W1 | [8448,9024) W2
//               [9024,9072) cs2 partial sums (3 colgroups x 16 k-chunks, atomicAdd;
//               cs2 zeroed by hipMemsetAsync before this launch).
// R7: cs2 was a 3-block serial 768-deep loop (R6 straggler, +31us) -> 48 parallel blocks.
#define CVT_B 6144
#define WQ_B 1728
#define W1_B 576
#define PREP_B (CVT_B + WQ_B + 2 * W1_B + 48)
__global__ __launch_bounds__(256) void prep(
    const float* __restrict__ base, unsigned short* __restrict__ base_bf,
    const float* __restrict__ Wqkv, unsigned short* __restrict__ Wqkvt,
    const float* __restrict__ W1, unsigned short* __restrict__ W1t,
    const float* __restrict__ W2, unsigned short* __restrict__ W2t,
    float* __restrict__ cs2) {
  __shared__ float t[32][33];
  int bid = blockIdx.x;
  int tid = threadIdx.x;
  if (bid < CVT_B) {
    int i = bid * 256 + tid;
    float4_t v = ((const float4_t*)base)[i];
    ushort4v o;
    o[0] = f2b(v[0]); o[1] = f2b(v[1]); o[2] = f2b(v[2]); o[3] = f2b(v[3]);
    ((ushort4v*)base_bf)[i] = o;
    return;
  }
  if (bid >= CVT_B + WQ_B + 2 * W1_B) {
    int c = bid - (CVT_B + WQ_B + 2 * W1_B);  // 0..47
    int colg = c % 3, kc = c / 3;             // 16 chunks of 48 k-rows
    int col = colg * 256 + tid;
    float s = 0.0f;
#pragma unroll 4
    for (int k = kc * 48; k < kc * 48 + 48; k++) s += W2[(size_t)k * DM_ + col];
    atomicAdd(&cs2[col], s);
    return;
  }
  const float* W; unsigned short* Wt; int N, rel;
  if (bid < CVT_B + WQ_B)      { W = Wqkv; Wt = Wqkvt; N = QKVN; rel = bid - CVT_B; }
  else if (bid < CVT_B + WQ_B + W1_B) { W = W1; Wt = W1t; N = DM_; rel = bid - CVT_B - WQ_B; }
  else                          { W = W2; Wt = W2t; N = DM_; rel = bid - CVT_B - WQ_B - W1_B; }
  int K = DM_;
  int n0 = (rel % (N / 32)) * 32, k0 = (rel / (N / 32)) * 32;
  int tx = tid & 31, ty = tid >> 5;  // ty 0..7
#pragma unroll
  for (int i = 0; i < 4; i++)
    t[ty + i * 8][tx] = W[(size_t)(k0 + ty + i * 8) * N + n0 + tx];
  __syncthreads();
#pragma unroll
  for (int i = 0; i < 4; i++)
    Wt[(size_t)(n0 + ty + i * 8) * K + k0 + tx] = f2b(t[tx][ty + i * 8]);
}

// ---------------- bf16 MFMA GEMM (128x128 tile, BK=128): QKV + fused V-transpose ----------
// XOR-swizzled LDS (16 chunks/row). Q cols pre-scaled by 0.125*log2(e).
// R3: 1D XCD-swizzled grid (each XCD owns 8 m x 18 n, m-fastest: A-panels L2-resident).
// R6: Q/K epilogue vectorized via per-wave LDS scratch.
__global__ __launch_bounds__(256, 2) void gemm_qkv(
    const unsigned short* __restrict__ A,
    const unsigned short* __restrict__ Bt,
    const float* __restrict__ bias,
    unsigned short* __restrict__ Cout,
    unsigned short* __restrict__ Vt,
    int M, int N, int K) {
  __shared__ __align__(16) unsigned short LDSbuf[2 * 128 * 128];  // As | Bs (64 KB)
  unsigned short* As = LDSbuf;
  unsigned short* Bs = LDSbuf + 128 * 128;
  int tid = threadIdx.x;
  int wave = tid >> 6, lane = tid & 63;
  int quad = lane >> 4, l16 = lane & 15;
  int sr4 = lane >> 4;                // staging row within 4-row op
  int c16 = lane & 15;                // staging chunk position
  int flat = blockIdx.x;              // 0..1151
  int xcd = flat & 7, widx = flat >> 3;          // widx 0..143
  int mb = xcd * 8 + (widx & 7);                 // 0..63
  int nb = widx >> 3;                            // 0..17
  int m0 = mb * 128, n0 = nb * 128;
  int wm = (wave >> 1) * 64, wn = (wave & 1) * 64;
  floatx4 acc[4][4] = {};

  for (int kb = 0; kb < K; kb += 128) {
#pragma unroll
    for (int i = 0; i < 8; i++) {
      int op = wave * 8 + i;
      int srow = op * 4 + sr4;
      int sc = c16 ^ (srow & 15);
      load_lds16(A + (size_t)(m0 + srow) * K + kb + sc * 8, (char*)As + op * 1024);
    }
#pragma unroll
    for (int i = 0; i < 8; i++) {
      int op = wave * 8 + i;
      int srow = op * 4 + sr4;
      int sc = c16 ^ (srow & 15);
      load_lds16(Bt + (size_t)(n0 + srow) * K + kb + sc * 8, (char*)Bs + op * 1024);
    }
    __syncthreads();  // drains vmcnt + barrier
#pragma unroll
    for (int ks = 0; ks < 4; ks++) {
      short8 af[4], bfr[4];
#pragma unroll
      for (int mt = 0; mt < 4; mt++)
        af[mt] = *(const short8*)(As + (wm + mt * 16 + l16) * 128 + ((ks * 4 + quad) ^ l16) * 8);
#pragma unroll
      for (int nt = 0; nt < 4; nt++)
        bfr[nt] = *(const short8*)(Bs + (wn + nt * 16 + l16) * 128 + ((ks * 4 + quad) ^ l16) * 8);
#pragma unroll
      for (int mt = 0; mt < 4; mt++)
#pragma unroll
        for (int nt = 0; nt < 4; nt++)
          acc[mt][nt] = __builtin_amdgcn_mfma_f32_16x16x32_bf16(af[mt], bfr[nt], acc[mt][nt], 0, 0, 0);
    }
    __syncthreads();  // also guarantees all ds_reads done before epilogue LDS reuse
  }

  unsigned short* scr = LDSbuf + wave * 4608;  // per-wave scratch, row stride 72 ushorts
  if (n0 < 2 * DM_) {
    // Q/K epilogue: assemble wave's 64x64 bf16 tile in scratch, store vectorized
    float qs = (n0 < DM_) ? 0.18033688011112042f : 1.0f;  // 0.125*log2(e) pre-scales Q
#pragma unroll
    for (int nt = 0; nt < 4; nt++) {
      float bv = bias[n0 + wn + nt * 16 + l16];
#pragma unroll
      for (int mt = 0; mt < 4; mt++)
#pragma unroll
        for (int r = 0; r < 4; r++)
          scr[(mt * 16 + quad * 4 + r) * 72 + nt * 16 + l16] = f2b((acc[mt][nt][r] + bv) * qs);
    }
#pragma unroll
    for (int it = 0; it < 8; it++) {
      int row = it * 8 + (lane >> 3);
      int ch = lane & 7;
      ushort8 w = *(const ushort8*)(scr + row * 72 + ch * 8);
      *(ushort8*)(Cout + (size_t)(m0 + wm + row) * N + n0 + wn + ch * 8) = w;
    }
  } else {
    // V epilogue: transpose + key-permute into Vt[(b*H+h)*64 + d][s]
    int h = (n0 + wn - 2 * DM_) >> 6;
    int b = m0 >> 11;
    int s_base = (m0 & (S_ - 1)) + wm;
#pragma unroll
    for (int nt = 0; nt < 4; nt++) {
      float bv = bias[n0 + wn + nt * 16 + l16];
      ushort8 v0, v1;
#pragma unroll
      for (int j = 0; j < 8; j++) {
        v0[j] = f2b(acc[j & 3][nt][j >> 2] + bv);
        v1[j] = f2b(acc[j & 3][nt][2 + (j >> 2)] + bv);
      }
      // pos = 16*quad + 4r + mt holds acc[mt][nt][r]  (perm(s)= (s&15)*4+(s>>4))
      *(ushort8*)(scr + (nt * 16 + l16) * 72 + quad * 16) = v0;
      *(ushort8*)(scr + (nt * 16 + l16) * 72 + quad * 16 + 8) = v1;
    }
#pragma unroll
    for (int it = 0; it < 8; it++) {
      int d = it * 8 + (lane >> 3);
      int ch = lane & 7;
      ushort8 w = *(const ushort8*)(scr + d * 72 + ch * 8);
      *(ushort8*)(Vt + ((size_t)(b * H_ + h) * 64 + d) * S_ + s_base + ch * 8) = w;
    }
  }
}

// ---------------- bf16 MFMA GEMM (64x128 tile, 4 blocks/CU): MLP GEMMs ----------------
// R3: 1D XCD-swizzled grid (each XCD owns 16 m x 6 n, m-fastest).
// R6 norm fusion:
//  EPI=1 (t1 = av@W1+b1+base): writes bf16 t1; atomically accumulates per-row
//         sum/sumsq of the ROUNDED values into rs/rq (norm1 stats).
//  EPI=2 (out2 = relu(hidden@W2+b2)+hidden, hidden=norm1(t1)=a*t1+c):
//         uses (a*t1+c)@W2 = a*(t1@W2) + c*colsum(W2); res=t1 re-affined for the
//         residual. normk<1> kernel + hbf round trip eliminated.
template <int EPI>
__global__ __launch_bounds__(256, 4) void gemm64(
    const unsigned short* __restrict__ A,
    const unsigned short* __restrict__ Bt,
    const float* __restrict__ bias,
    const unsigned short* __restrict__ res,
    unsigned short* __restrict__ Cout,
    float* __restrict__ rs, float* __restrict__ rq,
    const float* __restrict__ cs2,
    const float* __restrict__ nsc, const float* __restrict__ nbi,
    int M, int N, int K) {
  __shared__ __align__(16) unsigned short As[64 * 64];
  __shared__ __align__(16) unsigned short Bs[128 * 64];
  int tid = threadIdx.x;
  int wave = tid >> 6, lane = tid & 63;
  int quad = lane >> 4, l16 = lane & 15;
  int e = l16 & 7;
  int sr = lane >> 3;
  int sc = (lane & 7) ^ (sr & 7);
  int flat = blockIdx.x;              // 0..767
  int xcd = flat & 7, widx = flat >> 3;          // widx 0..95
  int mb = xcd * 16 + (widx & 15);               // 0..127
  int nb = widx >> 4;                            // 0..5
  int m0 = mb * 64, n0 = nb * 128;
  int wm = (wave >> 1) * 32, wn = (wave & 1) * 64;
  floatx4 acc[2][4] = {};

  for (int kb = 0; kb < K; kb += 64) {
#pragma unroll
    for (int i = 0; i < 2; i++) {
      int op = wave * 2 + i;  // 8 A ops
      load_lds16(A + (size_t)(m0 + op * 8 + sr) * K + kb + sc * 8, (char*)As + op * 1024);
    }
#pragma unroll
    for (int i = 0; i < 4; i++) {
      int op = wave * 4 + i;  // 16 B ops
      load_lds16(Bt + (size_t)(n0 + op * 8 + sr) * K + kb + sc * 8, (char*)Bs + op * 1024);
    }
    __syncthreads();
#pragma unroll
    for (int ks = 0; ks < 2; ks++) {
      short8 af[2], bfr[4];
#pragma unroll
      for (int mt = 0; mt < 2; mt++)
        af[mt] = *(const short8*)(As + (wm + mt * 16 + l16) * 64 + ((ks * 4 + quad) ^ e) * 8);
#pragma unroll
      for (int nt = 0; nt < 4; nt++)
        bfr[nt] = *(const short8*)(Bs + (wn + nt * 16 + l16) * 64 + ((ks * 4 + quad) ^ e) * 8);
#pragma unroll
      for (int mt = 0; mt < 2; mt++)
#pragma unroll
        for (int nt = 0; nt < 4; nt++)
          acc[mt][nt] = __builtin_amdgcn_mfma_f32_16x16x32_bf16(af[mt], bfr[nt], acc[mt][nt], 0, 0, 0);
    }
    __syncthreads();
  }
  const float inv768 = 1.0f / (float)DM_;
  if (EPI == 1) {
#pragma unroll
    for (int mt = 0; mt < 2; mt++) {
#pragma unroll
      for (int r = 0; r < 4; r++) {
        float srow = 0.0f, qrow = 0.0f;
        int row = m0 + wm + mt * 16 + quad * 4 + r;
#pragma unroll
        for (int nt = 0; nt < 4; nt++) {
          int col = n0 + wn + nt * 16 + l16;
          size_t idx = (size_t)row * N + col;
          float v = acc[mt][nt][r] + bias[col] + b2f(res[idx]);
          unsigned short vb = f2b(v);
          Cout[idx] = vb;
          float vr = b2f(vb);
          srow += vr; qrow += vr * vr;
        }
#pragma unroll
        for (int o = 1; o < 16; o <<= 1) {
          srow += __shfl_xor(srow, o);
          qrow += __shfl_xor(qrow, o);
        }
        if (l16 == 0) {
          atomicAdd(&rs[row], srow);
          atomicAdd(&rq[row], qrow);
        }
      }
    }
  } else {
    float sg = nsc[0], bg = nbi[0];
#pragma unroll
    for (int mt = 0; mt < 2; mt++) {
#pragma unroll
      for (int r = 0; r < 4; r++) {
        int row = m0 + wm + mt * 16 + quad * 4 + r;
        float mean = rs[row] * inv768;
        float a = rsqrtf(rq[row] * inv768 - mean * mean) * sg;
        float c = bg - mean * a;
#pragma unroll
        for (int nt = 0; nt < 4; nt++) {
          int col = n0 + wn + nt * 16 + l16;
          size_t idx = (size_t)row * N + col;
          float g = a * acc[mt][nt][r] + c * cs2[col] + bias[col];
          g = fmaxf(g, 0.0f);
          float hid = a * b2f(res[idx]) + c;
          Cout[idx] = f2b(g + hid);
        }
      }
    }
  }
}

// ---------------- flash attention: av = softmax(Q K^T / 8) V ----------------
// (R5 form, at its structural latency floor ~65us: every pipe <=40%, residency
//  pinned at ~2 blocks/CU across 32-50KB LDS variants. Untouched.)
__global__ __launch_bounds__(256, 3) void attn(
    const unsigned short* __restrict__ qkv,
    const unsigned short* __restrict__ Vt,
    unsigned short* __restrict__ av) {
  int flat = blockIdx.x;                  // 0..767
  int widx = (flat & 7) * 96 + (flat >> 3);
  int qt = widx & 15;    // q-tile 0..15 (128 rows)
  int bh = widx >> 4;    // 0..47
  int b = bh / H_, h = bh % H_;
  int row0 = b * S_ + qt * 128;
  __shared__ __align__(16) unsigned short Ks[2][64 * 64];
  __shared__ __align__(16) unsigned short Vs[2][64 * 64];
  __shared__ __align__(16) unsigned short Ps[4][32 * 72];  // row stride 144B; doubles as Q staging
  int tid = threadIdx.x;
  int wave = tid >> 6, lane = tid & 63;
  int quad = lane >> 4, l16 = lane & 15;
  int e = l16 & 7;
  int sr = lane >> 3;
  int sc = (lane & 7) ^ (sr & 7);

#pragma unroll
  for (int i = 0; i < 4; i++) {
    load_lds16(qkv + (size_t)(row0 + wave * 32 + i * 8 + sr) * QKVN + h * HD_ + sc * 8,
               (char*)Ps[wave] + i * 1024);
  }
  const unsigned short* kp = qkv + (size_t)(b * S_ + wave * 16 + sr) * QKVN + DM_ + h * HD_ + sc * 8;
  const unsigned short* vp = Vt + ((size_t)bh * 64 + wave * 16 + sr) * S_ + sc * 8;
  auto stageKV = [&](const unsigned short* kq, const unsigned short* vq, int buf) {
#pragma unroll
    for (int i = 0; i < 2; i++) {
      load_lds16(kq + (size_t)i * 8 * QKVN, (char*)Ks[buf] + wave * 2048 + i * 1024);
      load_lds16(vq + (size_t)i * 8 * S_, (char*)Vs[buf] + wave * 2048 + i * 1024);
    }
  };
  stageKV(kp, vp, 0);

  floatx4 accO[2][4] = {};
  floatx4 accL[2] = {};
  short8 ones;
#pragma unroll
  for (int j = 0; j < 8; j++) ones[j] = (short)0x3F80;  // bf16 1.0
  __syncthreads();  // Q + KV(0) staged (drains vmcnt)

  short8 qf[2][2];
#pragma unroll
  for (int mf = 0; mf < 2; mf++)
#pragma unroll
    for (int ks = 0; ks < 2; ks++)
      qf[mf][ks] = *(const short8*)(Ps[wave] + (mf * 16 + l16) * 64 + ((ks * 4 + quad) ^ e) * 8);

  int cur = 0;
  for (int kt = 0; kt < 32; kt++) {
    if (kt + 1 < 32) {
      kp += 64 * QKVN;
      vp += 64;
      stageKV(kp, vp, cur ^ 1);
    }
    floatx4 sv[2][4] = {};
    __builtin_amdgcn_s_setprio(1);
#pragma unroll
    for (int ks = 0; ks < 2; ks++)
#pragma unroll
      for (int nt = 0; nt < 4; nt++) {
        short8 kf = *(const short8*)(Ks[cur] + (nt * 16 + l16) * 64 + ((ks * 4 + quad) ^ e) * 8);
#pragma unroll
        for (int mf = 0; mf < 2; mf++)
          sv[mf][nt] = __builtin_amdgcn_mfma_f32_16x16x32_bf16(qf[mf][ks], kf, sv[mf][nt], 0, 0, 0);
      }
    __builtin_amdgcn_s_setprio(0);
#pragma unroll
    for (int mf = 0; mf < 2; mf++)
#pragma unroll
      for (int r = 0; r < 4; r++) {
        uint32_t u0 = fbits(__builtin_amdgcn_exp2f(sv[mf][0][r]));
        uint32_t u1 = fbits(__builtin_amdgcn_exp2f(sv[mf][1][r]));
        uint32_t u2 = fbits(__builtin_amdgcn_exp2f(sv[mf][2][r]));
        uint32_t u3 = fbits(__builtin_amdgcn_exp2f(sv[mf][3][r]));
        uint2 val;
        val.x = __builtin_amdgcn_perm(u1, u0, 0x07060302u);  // [u0.hi16, u1.hi16]
        val.y = __builtin_amdgcn_perm(u3, u2, 0x07060302u);  // [u2.hi16, u3.hi16]
        *(uint2*)(&Ps[wave][(mf * 16 + quad * 4 + r) * 72 + l16 * 4]) = val;
      }
    __builtin_amdgcn_s_setprio(1);
#pragma unroll
    for (int ks = 0; ks < 2; ks++) {
      short8 pf[2];
#pragma unroll
      for (int mf = 0; mf < 2; mf++) {
        pf[mf] = *(const short8*)(Ps[wave] + (mf * 16 + l16) * 72 + ks * 32 + quad * 8);
        accL[mf] = __builtin_amdgcn_mfma_f32_16x16x32_bf16(pf[mf], ones, accL[mf], 0, 0, 0);
      }
#pragma unroll
      for (int nt = 0; nt < 4; nt++) {
        short8 vf = *(const short8*)(Vs[cur] + (nt * 16 + l16) * 64 + ((ks * 4 + quad) ^ e) * 8);
#pragma unroll
        for (int mf = 0; mf < 2; mf++)
          accO[mf][nt] = __builtin_amdgcn_mfma_f32_16x16x32_bf16(pf[mf], vf, accO[mf][nt], 0, 0, 0);
      }
    }
    __builtin_amdgcn_s_setprio(0);
    __syncthreads();  // drains prefetch vmcnt; all waves done with cur
    cur ^= 1;
  }
#pragma unroll
  for (int mf = 0; mf < 2; mf++)
#pragma unroll
    for (int r = 0; r < 4; r++) {
      float inv = 1.0f / accL[mf][r];
      int row = row0 + wave * 32 + mf * 16 + quad * 4 + r;
#pragma unroll
      for (int nt = 0; nt < 4; nt++)
        av[(size_t)row * DM_ + h * HD_ + nt * 16 + l16] = f2b(accO[mf][nt][r] * inv);
    }
}

// ---------------- row norm: (x-mean)/std * scale + bias (bf16 input) ----------------
// WB=1: write bf16 only. WB=0: write f32 only (final output).
template <int WB>
__global__ __launch_bounds__(256) void normk(
    const unsigned short* __restrict__ X, const float* __restrict__ scale,
    const float* __restrict__ bias, float* __restrict__ Y,
    unsigned short* __restrict__ Ybf) {
  int row = blockIdx.x;
  const unsigned short* x = X + (size_t)row * DM_;
  int tid = threadIdx.x;
  int wave = tid >> 6, lane = tid & 63;
  float v[3];
#pragma unroll
  for (int i = 0; i < 3; i++) v[i] = b2f(x[tid + i * 256]);
  float s = v[0] + v[1] + v[2];
#pragma unroll
  for (int o = 32; o > 0; o >>= 1) s += __shfl_xor(s, o);
  __shared__ float red[4];
  if (lane == 0) red[wave] = s;
  __syncthreads();
  float mean = (red[0] + red[1] + red[2] + red[3]) * (1.0f / DM_);
  float ss = 0.0f;
#pragma unroll
  for (int i = 0; i < 3; i++) { v[i] -= mean; ss += v[i] * v[i]; }
#pragma unroll
  for (int o = 32; o > 0; o >>= 1) ss += __shfl_xor(ss, o);
  __syncthreads();
  if (lane == 0) red[wave] = ss;
  __syncthreads();
  float var = (red[0] + red[1] + red[2] + red[3]) * (1.0f / DM_);
  float rstd = rsqrtf(var);
  float sg = scale[0], bg = bias[0];
#pragma unroll
  for (int i = 0; i < 3; i++) {
    float y = v[i] * rstd * sg + bg;
    if (WB) Ybf[(size_t)row * DM_ + tid + i * 256] = f2b(y);
    else    Y[(size_t)row * DM_ + tid + i * 256] = y;
  }
}

extern "C" void kernel_launch(void* const* d_in, const int* in_sizes, int n_in,
                              void* d_out, int out_size, void* d_ws, size_t ws_size,
                              hipStream_t stream) {
  const float* base = (const float*)d_in[0];
  const float* Wqkv = (const float*)d_in[1];
  const float* bqkv = (const float*)d_in[2];
  const float* W1 = (const float*)d_in[3];
  const float* b1 = (const float*)d_in[4];
  const float* W2 = (const float*)d_in[5];
  const float* b2 = (const float*)d_in[6];
  const float* n1s = (const float*)d_in[7];
  const float* n1b = (const float*)d_in[8];
  const float* n2s = (const float*)d_in[9];
  const float* n2b = (const float*)d_in[10];
  float* out = (float*)d_out;

  char* ws = (char*)d_ws;
  size_t off = 0;
  auto alloc = [&](size_t bytes) {
    char* p = ws + off;
    off = (off + bytes + 255) & ~(size_t)255;
    return p;
  };
  unsigned short* base_bf = (unsigned short*)alloc((size_t)ROWS * DM_ * 2);
  unsigned short* Wqkvt = (unsigned short*)alloc((size_t)QKVN * DM_ * 2);
  unsigned short* W1t = (unsigned short*)alloc((size_t)DM_ * DM_ * 2);
  unsigned short* W2t = (unsigned short*)alloc((size_t)DM_ * DM_ * 2);
  unsigned short* qkvb = (unsigned short*)alloc((size_t)ROWS * QKVN * 2);
  unsigned short* Vtb = (unsigned short*)alloc((size_t)B_ * H_ * HD_ * S_ * 2);
  unsigned short* avb = (unsigned short*)alloc((size_t)ROWS * DM_ * 2);
  unsigned short* t1b = (unsigned short*)alloc((size_t)ROWS * DM_ * 2);
  unsigned short* hbf = (unsigned short*)alloc((size_t)ROWS * DM_ * 2);  // gemm64<2> output
  float* rs1 = (float*)alloc((size_t)ROWS * 4);
  float* rq1 = (float*)alloc((size_t)ROWS * 4);
  float* cs2 = (float*)alloc((size_t)DM_ * 4);

  // zero rs1|rq1|cs2 (contiguous, 256B-aligned allocs): replaces R6's zero-blocks
  // and removes the zero-vs-atomic same-launch race. Memset-on-stream is capture-safe.
  hipMemsetAsync(rs1, 0, (size_t)(ROWS * 2 + DM_) * 4, stream);

  prep<<<PREP_B, 256, 0, stream>>>(
      base, base_bf, Wqkv, Wqkvt, W1, W1t, W2, W2t, cs2);
  gemm_qkv<<<dim3((QKVN / 128) * (ROWS / 128)), 256, 0, stream>>>(
      base_bf, Wqkvt, bqkv, qkvb, Vtb, ROWS, QKVN, DM_);
  attn<<<dim3((S_ / 128) * (B_ * H_)), 256, 0, stream>>>(qkvb, Vtb, avb);  // 768 blocks
  gemm64<1><<<dim3((DM_ / 128) * (ROWS / 64)), 256, 0, stream>>>(
      avb, W1t, b1, base_bf, t1b, rs1, rq1, nullptr, nullptr, nullptr, ROWS, DM_, DM_);
  gemm64<2><<<dim3((DM_ / 128) * (ROWS / 64)), 256, 0, stream>>>(
      t1b, W2t, b2, t1b, hbf, rs1, rq1, cs2, n1s, n1b, ROWS, DM_, DM_);
  normk<0><<<ROWS, 256, 0, stream>>>(hbf, n2s, n2b, out, nullptr);
}

// Round 8
// 246.426 us; speedup vs baseline: 1.1267x; 1.0487x over previous
//
#include <hip/hip_runtime.h>
#include <hip/hip_bf16.h>
#include <stdint.h>

#define B_ 4
#define S_ 2048
#define DM_ 768
#define H_ 12
#define HD_ 64
#define ROWS (B_*S_)      // 8192
#define QKVN (3*DM_)      // 2304

typedef __attribute__((ext_vector_type(8))) short short8;
typedef __attribute__((ext_vector_type(4))) float floatx4;
typedef __attribute__((ext_vector_type(8))) unsigned short ushort8;
typedef __attribute__((ext_vector_type(4))) unsigned short ushort4v;
typedef __attribute__((ext_vector_type(4))) float float4_t;

__device__ __forceinline__ unsigned short f2b(float f) {
  union { float f; uint32_t u; } x; x.f = f;
  uint32_t r = x.u + 0x7FFFu + ((x.u >> 16) & 1u);
  return (unsigned short)(r >> 16);
}
__device__ __forceinline__ float b2f(unsigned short u) {
  union { uint32_t u; float f; } x; x.u = ((uint32_t)u) << 16; return x.f;
}
__device__ __forceinline__ uint32_t fbits(float f) {
  union { float f; uint32_t u; } x; x.f = f; return x.u;
}

// async global->LDS, 16B per lane. LDS dest is wave-uniform base + lane*16.
__device__ __forceinline__ void load_lds16(const void* g, void* l) {
  __builtin_amdgcn_global_load_lds(
      (const __attribute__((address_space(1))) uint32_t*)g,
      (__attribute__((address_space(3))) uint32_t*)l, 16, 0, 0);
}

// ---------------- fused prep: base cast + 3 weight transposes ----------------
// block ranges: [0,6144) cvt | [6144,7872) Wqkv | [7872,8448) W1 | [8448,9024) W2
#define CVT_B 6144
#define WQ_B 1728
#define W1_B 576
__global__ __launch_bounds__(256) void prep(
    const float* __restrict__ base, unsigned short* __restrict__ base_bf,
    const float* __restrict__ Wqkv, unsigned short* __restrict__ Wqkvt,
    const float* __restrict__ W1, unsigned short* __restrict__ W1t,
    const float* __restrict__ W2, unsigned short* __restrict__ W2t) {
  __shared__ float t[32][33];
  int bid = blockIdx.x;
  int tid = threadIdx.x;
  if (bid < CVT_B) {
    int i = bid * 256 + tid;
    float4_t v = ((const float4_t*)base)[i];
    ushort4v o;
    o[0] = f2b(v[0]); o[1] = f2b(v[1]); o[2] = f2b(v[2]); o[3] = f2b(v[3]);
    ((ushort4v*)base_bf)[i] = o;
    return;
  }
  const float* W; unsigned short* Wt; int N, rel;
  if (bid < CVT_B + WQ_B)      { W = Wqkv; Wt = Wqkvt; N = QKVN; rel = bid - CVT_B; }
  else if (bid < CVT_B + WQ_B + W1_B) { W = W1; Wt = W1t; N = DM_; rel = bid - CVT_B - WQ_B; }
  else                          { W = W2; Wt = W2t; N = DM_; rel = bid - CVT_B - WQ_B - W1_B; }
  int K = DM_;
  int n0 = (rel % (N / 32)) * 32, k0 = (rel / (N / 32)) * 32;
  int tx = tid & 31, ty = tid >> 5;  // ty 0..7
#pragma unroll
  for (int i = 0; i < 4; i++)
    t[ty + i * 8][tx] = W[(size_t)(k0 + ty + i * 8) * N + n0 + tx];
  __syncthreads();
#pragma unroll
  for (int i = 0; i < 4; i++)
    Wt[(size_t)(n0 + ty + i * 8) * K + k0 + tx] = f2b(t[tx][ty + i * 8]);
}

// ---------------- bf16 MFMA GEMM (128x128 tile, BK=128): QKV + fused V-transpose ----------
// XOR-swizzled LDS (16 chunks/row): chunk c of row r stored at position c^(r&15).
// Q cols pre-scaled by 0.125*log2(e); V-blocks write transposed permuted Vt directly.
// R3: 1D XCD-swizzled grid (each XCD owns 8 m x 18 n, m-fastest: A-panels L2-resident).
// R8: Q/K epilogue vectorized via per-wave LDS scratch (b16 LDS writes -> same-wave
//     b128 reads -> dwordx4 coalesced stores; 32x fewer store transactions). Values
//     bit-identical to the R3 scalar path. Everything else is the R3 (244.5us) source.
__global__ __launch_bounds__(256, 2) void gemm_qkv(
    const unsigned short* __restrict__ A,
    const unsigned short* __restrict__ Bt,
    const float* __restrict__ bias,
    unsigned short* __restrict__ Cout,
    unsigned short* __restrict__ Vt,
    int M, int N, int K) {
  __shared__ __align__(16) unsigned short LDSbuf[2 * 128 * 128];  // As | Bs (64 KB)
  unsigned short* As = LDSbuf;
  unsigned short* Bs = LDSbuf + 128 * 128;
  int tid = threadIdx.x;
  int wave = tid >> 6, lane = tid & 63;
  int quad = lane >> 4, l16 = lane & 15;
  int sr4 = lane >> 4;                // staging row within 4-row op
  int c16 = lane & 15;                // staging chunk position
  int flat = blockIdx.x;              // 0..1151
  int xcd = flat & 7, widx = flat >> 3;          // widx 0..143
  int mb = xcd * 8 + (widx & 7);                 // 0..63
  int nb = widx >> 3;                            // 0..17
  int m0 = mb * 128, n0 = nb * 128;
  int wm = (wave >> 1) * 64, wn = (wave & 1) * 64;
  floatx4 acc[4][4] = {};

  for (int kb = 0; kb < K; kb += 128) {
#pragma unroll
    for (int i = 0; i < 8; i++) {
      int op = wave * 8 + i;
      int srow = op * 4 + sr4;
      int sc = c16 ^ (srow & 15);
      load_lds16(A + (size_t)(m0 + srow) * K + kb + sc * 8, (char*)As + op * 1024);
    }
#pragma unroll
    for (int i = 0; i < 8; i++) {
      int op = wave * 8 + i;
      int srow = op * 4 + sr4;
      int sc = c16 ^ (srow & 15);
      load_lds16(Bt + (size_t)(n0 + srow) * K + kb + sc * 8, (char*)Bs + op * 1024);
    }
    __syncthreads();  // drains vmcnt + barrier
#pragma unroll
    for (int ks = 0; ks < 4; ks++) {
      short8 af[4], bfr[4];
#pragma unroll
      for (int mt = 0; mt < 4; mt++)
        af[mt] = *(const short8*)(As + (wm + mt * 16 + l16) * 128 + ((ks * 4 + quad) ^ l16) * 8);
#pragma unroll
      for (int nt = 0; nt < 4; nt++)
        bfr[nt] = *(const short8*)(Bs + (wn + nt * 16 + l16) * 128 + ((ks * 4 + quad) ^ l16) * 8);
#pragma unroll
      for (int mt = 0; mt < 4; mt++)
#pragma unroll
        for (int nt = 0; nt < 4; nt++)
          acc[mt][nt] = __builtin_amdgcn_mfma_f32_16x16x32_bf16(af[mt], bfr[nt], acc[mt][nt], 0, 0, 0);
    }
    __syncthreads();  // also guarantees all ds_reads done before epilogue LDS reuse
  }

  unsigned short* scr = LDSbuf + wave * 4608;  // per-wave scratch, row stride 72 ushorts
  if (n0 < 2 * DM_) {
    // Q/K epilogue: assemble wave's 64x64 bf16 tile in scratch, store vectorized
    float qs = (n0 < DM_) ? 0.18033688011112042f : 1.0f;  // 0.125*log2(e) pre-scales Q
#pragma unroll
    for (int nt = 0; nt < 4; nt++) {
      float bv = bias[n0 + wn + nt * 16 + l16];
#pragma unroll
      for (int mt = 0; mt < 4; mt++)
#pragma unroll
        for (int r = 0; r < 4; r++)
          scr[(mt * 16 + quad * 4 + r) * 72 + nt * 16 + l16] = f2b((acc[mt][nt][r] + bv) * qs);
    }
#pragma unroll
    for (int it = 0; it < 8; it++) {
      int row = it * 8 + (lane >> 3);
      int ch = lane & 7;
      ushort8 w = *(const ushort8*)(scr + row * 72 + ch * 8);
      *(ushort8*)(Cout + (size_t)(m0 + wm + row) * N + n0 + wn + ch * 8) = w;
    }
  } else {
    // V epilogue: transpose + key-permute into Vt[(b*H+h)*64 + d][s]
    int h = (n0 + wn - 2 * DM_) >> 6;
    int b = m0 >> 11;
    int s_base = (m0 & (S_ - 1)) + wm;
#pragma unroll
    for (int nt = 0; nt < 4; nt++) {
      float bv = bias[n0 + wn + nt * 16 + l16];
      ushort8 v0, v1;
#pragma unroll
      for (int j = 0; j < 8; j++) {
        v0[j] = f2b(acc[j & 3][nt][j >> 2] + bv);
        v1[j] = f2b(acc[j & 3][nt][2 + (j >> 2)] + bv);
      }
      // pos = 16*quad + 4r + mt holds acc[mt][nt][r]  (perm(s)= (s&15)*4+(s>>4))
      *(ushort8*)(scr + (nt * 16 + l16) * 72 + quad * 16) = v0;
      *(ushort8*)(scr + (nt * 16 + l16) * 72 + quad * 16 + 8) = v1;
    }
    // read back rows of d, write coalesced to Vt (same-wave: compiler inserts lgkmcnt)
#pragma unroll
    for (int it = 0; it < 8; it++) {
      int d = it * 8 + (lane >> 3);
      int ch = lane & 7;
      ushort8 w = *(const ushort8*)(scr + d * 72 + ch * 8);
      *(ushort8*)(Vt + ((size_t)(b * H_ + h) * 64 + d) * S_ + s_base + ch * 8) = w;
    }
  }
}

// ---------------- bf16 MFMA GEMM (64x128 tile, 4 blocks/CU): MLP GEMMs ----------------
// EPI=1: bias + res(bf16) -> bf16 out. EPI=2: relu(bias) + res(bf16) -> bf16 out.
// R3: 1D XCD-swizzled grid (each XCD owns 16 m x 6 n, m-fastest).
template <int EPI>
__global__ __launch_bounds__(256, 4) void gemm64(
    const unsigned short* __restrict__ A,
    const unsigned short* __restrict__ Bt,
    const float* __restrict__ bias,
    const unsigned short* __restrict__ res,
    unsigned short* __restrict__ Cout,
    int M, int N, int K) {
  __shared__ __align__(16) unsigned short As[64 * 64];
  __shared__ __align__(16) unsigned short Bs[128 * 64];
  int tid = threadIdx.x;
  int wave = tid >> 6, lane = tid & 63;
  int quad = lane >> 4, l16 = lane & 15;
  int e = l16 & 7;
  int sr = lane >> 3;
  int sc = (lane & 7) ^ (sr & 7);
  int flat = blockIdx.x;              // 0..767
  int xcd = flat & 7, widx = flat >> 3;          // widx 0..95
  int mb = xcd * 16 + (widx & 15);               // 0..127
  int nb = widx >> 4;                            // 0..5
  int m0 = mb * 64, n0 = nb * 128;
  int wm = (wave >> 1) * 32, wn = (wave & 1) * 64;
  floatx4 acc[2][4] = {};

  for (int kb = 0; kb < K; kb += 64) {
#pragma unroll
    for (int i = 0; i < 2; i++) {
      int op = wave * 2 + i;  // 8 A ops
      load_lds16(A + (size_t)(m0 + op * 8 + sr) * K + kb + sc * 8, (char*)As + op * 1024);
    }
#pragma unroll
    for (int i = 0; i < 4; i++) {
      int op = wave * 4 + i;  // 16 B ops
      load_lds16(Bt + (size_t)(n0 + op * 8 + sr) * K + kb + sc * 8, (char*)Bs + op * 1024);
    }
    __syncthreads();
#pragma unroll
    for (int ks = 0; ks < 2; ks++) {
      short8 af[2], bfr[4];
#pragma unroll
      for (int mt = 0; mt < 2; mt++)
        af[mt] = *(const short8*)(As + (wm + mt * 16 + l16) * 64 + ((ks * 4 + quad) ^ e) * 8);
#pragma unroll
      for (int nt = 0; nt < 4; nt++)
        bfr[nt] = *(const short8*)(Bs + (wn + nt * 16 + l16) * 64 + ((ks * 4 + quad) ^ e) * 8);
#pragma unroll
      for (int mt = 0; mt < 2; mt++)
#pragma unroll
        for (int nt = 0; nt < 4; nt++)
          acc[mt][nt] = __builtin_amdgcn_mfma_f32_16x16x32_bf16(af[mt], bfr[nt], acc[mt][nt], 0, 0, 0);
    }
    __syncthreads();
  }
#pragma unroll
  for (int mt = 0; mt < 2; mt++) {
#pragma unroll
    for (int nt = 0; nt < 4; nt++) {
#pragma unroll
      for (int r = 0; r < 4; r++) {
        int row = m0 + wm + mt * 16 + quad * 4 + r;
        int col = n0 + wn + nt * 16 + l16;
        size_t idx = (size_t)row * N + col;
        float v = acc[mt][nt][r] + bias[col];
        if (EPI == 2) v = fmaxf(v, 0.0f);
        v += b2f(res[idx]);
        Cout[idx] = f2b(v);
      }
    }
  }
}

// ---------------- flash attention: av = softmax(Q K^T / 8) V ----------------
// R3 form (best measured): 4 waves x 32 q-rows; XCD-contiguous 1D grid; setprio;
// prefetch after QK. Structural latency floor ~65us (pipes <=40%, 2 blocks/CU
// pinned across 32-50KB LDS variants).
__global__ __launch_bounds__(256, 3) void attn(
    const unsigned short* __restrict__ qkv,
    const unsigned short* __restrict__ Vt,
    unsigned short* __restrict__ av) {
  int flat = blockIdx.x;                  // 0..767
  int widx = (flat & 7) * 96 + (flat >> 3);
  int qt = widx & 15;    // q-tile 0..15 (128 rows)
  int bh = widx >> 4;    // 0..47
  int b = bh / H_, h = bh % H_;
  int row0 = b * S_ + qt * 128;
  __shared__ __align__(16) unsigned short Ks[2][64 * 64];
  __shared__ __align__(16) unsigned short Vs[2][64 * 64];
  __shared__ __align__(16) unsigned short Ps[4][32 * 72];  // row stride 144B; doubles as Q staging
  int tid = threadIdx.x;
  int wave = tid >> 6, lane = tid & 63;
  int quad = lane >> 4, l16 = lane & 15;
  int e = l16 & 7;
  int sr = lane >> 3;
  int sc = (lane & 7) ^ (sr & 7);

#pragma unroll
  for (int i = 0; i < 4; i++) {
    load_lds16(qkv + (size_t)(row0 + wave * 32 + i * 8 + sr) * QKVN + h * HD_ + sc * 8,
               (char*)Ps[wave] + i * 1024);
  }
  const unsigned short* kp = qkv + (size_t)(b * S_ + wave * 16 + sr) * QKVN + DM_ + h * HD_ + sc * 8;
  const unsigned short* vp = Vt + ((size_t)bh * 64 + wave * 16 + sr) * S_ + sc * 8;
  auto stageKV = [&](const unsigned short* kq, const unsigned short* vq, int buf) {
#pragma unroll
    for (int i = 0; i < 2; i++) {
      load_lds16(kq + (size_t)i * 8 * QKVN, (char*)Ks[buf] + wave * 2048 + i * 1024);
      load_lds16(vq + (size_t)i * 8 * S_, (char*)Vs[buf] + wave * 2048 + i * 1024);
    }
  };
  stageKV(kp, vp, 0);

  floatx4 accO[2][4] = {};
  floatx4 accL[2] = {};
  short8 ones;
#pragma unroll
  for (int j = 0; j < 8; j++) ones[j] = (short)0x3F80;  // bf16 1.0
  __syncthreads();  // Q + KV(0) staged (drains vmcnt)

  short8 qf[2][2];
#pragma unroll
  for (int mf = 0; mf < 2; mf++)
#pragma unroll
    for (int ks = 0; ks < 2; ks++)
      qf[mf][ks] = *(const short8*)(Ps[wave] + (mf * 16 + l16) * 64 + ((ks * 4 + quad) ^ e) * 8);

  int cur = 0;
  for (int kt = 0; kt < 32; kt++) {
    floatx4 sv[2][4] = {};
    __builtin_amdgcn_s_setprio(1);
#pragma unroll
    for (int ks = 0; ks < 2; ks++)
#pragma unroll
      for (int nt = 0; nt < 4; nt++) {
        short8 kf = *(const short8*)(Ks[cur] + (nt * 16 + l16) * 64 + ((ks * 4 + quad) ^ e) * 8);
#pragma unroll
        for (int mf = 0; mf < 2; mf++)
          sv[mf][nt] = __builtin_amdgcn_mfma_f32_16x16x32_bf16(qf[mf][ks], kf, sv[mf][nt], 0, 0, 0);
      }
    __builtin_amdgcn_s_setprio(0);
    // prefetch next K/V now: overlaps softmax + PV below
    if (kt + 1 < 32) {
      kp += 64 * QKVN;
      vp += 64;
      stageKV(kp, vp, cur ^ 1);
    }
    // p = exp2(sv) (scale folded into Q); pack 4 bf16 -> b64 write
#pragma unroll
    for (int mf = 0; mf < 2; mf++)
#pragma unroll
      for (int r = 0; r < 4; r++) {
        uint32_t u0 = fbits(__builtin_amdgcn_exp2f(sv[mf][0][r]));
        uint32_t u1 = fbits(__builtin_amdgcn_exp2f(sv[mf][1][r]));
        uint32_t u2 = fbits(__builtin_amdgcn_exp2f(sv[mf][2][r]));
        uint32_t u3 = fbits(__builtin_amdgcn_exp2f(sv[mf][3][r]));
        uint2 val;
        val.x = __builtin_amdgcn_perm(u1, u0, 0x07060302u);  // [u0.hi16, u1.hi16]
        val.y = __builtin_amdgcn_perm(u3, u2, 0x07060302u);  // [u2.hi16, u3.hi16]
        *(uint2*)(&Ps[wave][(mf * 16 + quad * 4 + r) * 72 + l16 * 4]) = val;
      }
    __builtin_amdgcn_s_setprio(1);
#pragma unroll
    for (int ks = 0; ks < 2; ks++) {
      short8 pf[2];
#pragma unroll
      for (int mf = 0; mf < 2; mf++) {
        pf[mf] = *(const short8*)(Ps[wave] + (mf * 16 + l16) * 72 + ks * 32 + quad * 8);
        accL[mf] = __builtin_amdgcn_mfma_f32_16x16x32_bf16(pf[mf], ones, accL[mf], 0, 0, 0);
      }
#pragma unroll
      for (int nt = 0; nt < 4; nt++) {
        short8 vf = *(const short8*)(Vs[cur] + (nt * 16 + l16) * 64 + ((ks * 4 + quad) ^ e) * 8);
#pragma unroll
        for (int mf = 0; mf < 2; mf++)
          accO[mf][nt] = __builtin_amdgcn_mfma_f32_16x16x32_bf16(pf[mf], vf, accO[mf][nt], 0, 0, 0);
      }
    }
    __builtin_amdgcn_s_setprio(0);
    __syncthreads();  // drains prefetch vmcnt; all waves done with cur
    cur ^= 1;
  }
#pragma unroll
  for (int mf = 0; mf < 2; mf++)
#pragma unroll
    for (int r = 0; r < 4; r++) {
      float inv = 1.0f / accL[mf][r];
      int row = row0 + wave * 32 + mf * 16 + quad * 4 + r;
#pragma unroll
      for (int nt = 0; nt < 4; nt++)
        av[(size_t)row * DM_ + h * HD_ + nt * 16 + l16] = f2b(accO[mf][nt][r] * inv);
    }
}

// ---------------- row norm: (x-mean)/std * scale + bias (bf16 input) ----------------
// WB=1: write bf16 only. WB=0: write f32 only (final output).
template <int WB>
__global__ __launch_bounds__(256) void normk(
    const unsigned short* __restrict__ X, const float* __restrict__ scale,
    const float* __restrict__ bias, float* __restrict__ Y,
    unsigned short* __restrict__ Ybf) {
  int row = blockIdx.x;
  const unsigned short* x = X + (size_t)row * DM_;
  int tid = threadIdx.x;
  int wave = tid >> 6, lane = tid & 63;
  float v[3];
#pragma unroll
  for (int i = 0; i < 3; i++) v[i] = b2f(x[tid + i * 256]);
  float s = v[0] + v[1] + v[2];
#pragma unroll
  for (int o = 32; o > 0; o >>= 1) s += __shfl_xor(s, o);
  __shared__ float red[4];
  if (lane == 0) red[wave] = s;
  __syncthreads();
  float mean = (red[0] + red[1] + red[2] + red[3]) * (1.0f / DM_);
  float ss = 0.0f;
#pragma unroll
  for (int i = 0; i < 3; i++) { v[i] -= mean; ss += v[i] * v[i]; }
#pragma unroll
  for (int o = 32; o > 0; o >>= 1) ss += __shfl_xor(ss, o);
  __syncthreads();
  if (lane == 0) red[wave] = ss;
  __syncthreads();
  float var = (red[0] + red[1] + red[2] + red[3]) * (1.0f / DM_);
  float rstd = rsqrtf(var);
  float sg = scale[0], bg = bias[0];
#pragma unroll
  for (int i = 0; i < 3; i++) {
    float y = v[i] * rstd * sg + bg;
    if (WB) Ybf[(size_t)row * DM_ + tid + i * 256] = f2b(y);
    else    Y[(size_t)row * DM_ + tid + i * 256] = y;
  }
}

extern "C" void kernel_launch(void* const* d_in, const int* in_sizes, int n_in,
                              void* d_out, int out_size, void* d_ws, size_t ws_size,
                              hipStream_t stream) {
  const float* base = (const float*)d_in[0];
  const float* Wqkv = (const float*)d_in[1];
  const float* bqkv = (const float*)d_in[2];
  const float* W1 = (const float*)d_in[3];
  const float* b1 = (const float*)d_in[4];
  const float* W2 = (const float*)d_in[5];
  const float* b2 = (const float*)d_in[6];
  const float* n1s = (const float*)d_in[7];
  const float* n1b = (const float*)d_in[8];
  const float* n2s = (const float*)d_in[9];
  const float* n2b = (const float*)d_in[10];
  float* out = (float*)d_out;

  char* ws = (char*)d_ws;
  size_t off = 0;
  auto alloc = [&](size_t bytes) {
    char* p = ws + off;
    off = (off + bytes + 255) & ~(size_t)255;
    return p;
  };
  unsigned short* base_bf = (unsigned short*)alloc((size_t)ROWS * DM_ * 2);
  unsigned short* Wqkvt = (unsigned short*)alloc((size_t)QKVN * DM_ * 2);
  unsigned short* W1t = (unsigned short*)alloc((size_t)DM_ * DM_ * 2);
  unsigned short* W2t = (unsigned short*)alloc((size_t)DM_ * DM_ * 2);
  unsigned short* qkvb = (unsigned short*)alloc((size_t)ROWS * QKVN * 2);
  unsigned short* Vtb = (unsigned short*)alloc((size_t)B_ * H_ * HD_ * S_ * 2);
  unsigned short* avb = (unsigned short*)alloc((size_t)ROWS * DM_ * 2);
  unsigned short* t1b = (unsigned short*)alloc((size_t)ROWS * DM_ * 2);   // reused for t2
  unsigned short* hbf = (unsigned short*)alloc((size_t)ROWS * DM_ * 2);

  prep<<<CVT_B + WQ_B + 2 * W1_B, 256, 0, stream>>>(
      base, base_bf, Wqkv, Wqkvt, W1, W1t, W2, W2t);
  gemm_qkv<<<dim3((QKVN / 128) * (ROWS / 128)), 256, 0, stream>>>(
      base_bf, Wqkvt, bqkv, qkvb, Vtb, ROWS, QKVN, DM_);
  attn<<<dim3((S_ / 128) * (B_ * H_)), 256, 0, stream>>>(qkvb, Vtb, avb);  // 768 blocks
  gemm64<1><<<dim3((DM_ / 128) * (ROWS / 64)), 256, 0, stream>>>(
      avb, W1t, b1, base_bf, t1b, ROWS, DM_, DM_);
  normk<1><<<ROWS, 256, 0, stream>>>(t1b, n1s, n1b, nullptr, hbf);
  gemm64<2><<<dim3((DM_ / 128) * (ROWS / 64)), 256, 0, stream>>>(
      hbf, W2t, b2, hbf, t1b, ROWS, DM_, DM_);
  normk<0><<<ROWS, 256, 0, stream>>>(t1b, n2s, n2b, out, nullptr);
}

// Round 9
// 243.438 us; speedup vs baseline: 1.1406x; 1.0123x over previous
//
#include <hip/hip_runtime.h>
#include <hip/hip_bf16.h>
#include <stdint.h>

#define B_ 4
#define S_ 2048
#define DM_ 768
#define H_ 12
#define HD_ 64
#define ROWS (B_*S_)      // 8192
#define QKVN (3*DM_)      // 2304

typedef __attribute__((ext_vector_type(8))) short short8;
typedef __attribute__((ext_vector_type(4))) float floatx4;
typedef __attribute__((ext_vector_type(8))) unsigned short ushort8;
typedef __attribute__((ext_vector_type(4))) unsigned short ushort4v;
typedef __attribute__((ext_vector_type(4))) float float4_t;

__device__ __forceinline__ unsigned short f2b(float f) {
  union { float f; uint32_t u; } x; x.f = f;
  uint32_t r = x.u + 0x7FFFu + ((x.u >> 16) & 1u);
  return (unsigned short)(r >> 16);
}
__device__ __forceinline__ float b2f(unsigned short u) {
  union { uint32_t u; float f; } x; x.u = ((uint32_t)u) << 16; return x.f;
}
__device__ __forceinline__ uint32_t fbits(float f) {
  union { float f; uint32_t u; } x; x.f = f; return x.u;
}

// async global->LDS, 16B per lane. LDS dest is wave-uniform base + lane*16.
__device__ __forceinline__ void load_lds16(const void* g, void* l) {
  __builtin_amdgcn_global_load_lds(
      (const __attribute__((address_space(1))) uint32_t*)g,
      (__attribute__((address_space(3))) uint32_t*)l, 16, 0, 0);
}

// ---------------- fused prep: base cast + 3 weight transposes ----------------
// block ranges: [0,6144) cvt | [6144,7872) Wqkv | [7872,8448) W1 | [8448,9024) W2
#define CVT_B 6144
#define WQ_B 1728
#define W1_B 576
__global__ __launch_bounds__(256) void prep(
    const float* __restrict__ base, unsigned short* __restrict__ base_bf,
    const float* __restrict__ Wqkv, unsigned short* __restrict__ Wqkvt,
    const float* __restrict__ W1, unsigned short* __restrict__ W1t,
    const float* __restrict__ W2, unsigned short* __restrict__ W2t) {
  __shared__ float t[32][33];
  int bid = blockIdx.x;
  int tid = threadIdx.x;
  if (bid < CVT_B) {
    int i = bid * 256 + tid;
    float4_t v = ((const float4_t*)base)[i];
    ushort4v o;
    o[0] = f2b(v[0]); o[1] = f2b(v[1]); o[2] = f2b(v[2]); o[3] = f2b(v[3]);
    ((ushort4v*)base_bf)[i] = o;
    return;
  }
  const float* W; unsigned short* Wt; int N, rel;
  if (bid < CVT_B + WQ_B)      { W = Wqkv; Wt = Wqkvt; N = QKVN; rel = bid - CVT_B; }
  else if (bid < CVT_B + WQ_B + W1_B) { W = W1; Wt = W1t; N = DM_; rel = bid - CVT_B - WQ_B; }
  else                          { W = W2; Wt = W2t; N = DM_; rel = bid - CVT_B - WQ_B - W1_B; }
  int K = DM_;
  int n0 = (rel % (N / 32)) * 32, k0 = (rel / (N / 32)) * 32;
  int tx = tid & 31, ty = tid >> 5;  // ty 0..7
#pragma unroll
  for (int i = 0; i < 4; i++)
    t[ty + i * 8][tx] = W[(size_t)(k0 + ty + i * 8) * N + n0 + tx];
  __syncthreads();
#pragma unroll
  for (int i = 0; i < 4; i++)
    Wt[(size_t)(n0 + ty + i * 8) * K + k0 + tx] = f2b(t[tx][ty + i * 8]);
}

// ---------------- bf16 MFMA GEMM (128x128 tile, BK=128): QKV + fused V-transpose ----------
// XOR-swizzled LDS; Q cols pre-scaled by 0.125*log2(e); V-blocks write permuted Vt.
// R3: 1D XCD-swizzled grid. R8: vectorized Q/K epilogue via per-wave LDS scratch.
__global__ __launch_bounds__(256, 2) void gemm_qkv(
    const unsigned short* __restrict__ A,
    const unsigned short* __restrict__ Bt,
    const float* __restrict__ bias,
    unsigned short* __restrict__ Cout,
    unsigned short* __restrict__ Vt,
    int M, int N, int K) {
  __shared__ __align__(16) unsigned short LDSbuf[2 * 128 * 128];  // As | Bs (64 KB)
  unsigned short* As = LDSbuf;
  unsigned short* Bs = LDSbuf + 128 * 128;
  int tid = threadIdx.x;
  int wave = tid >> 6, lane = tid & 63;
  int quad = lane >> 4, l16 = lane & 15;
  int sr4 = lane >> 4;
  int c16 = lane & 15;
  int flat = blockIdx.x;              // 0..1151
  int xcd = flat & 7, widx = flat >> 3;          // widx 0..143
  int mb = xcd * 8 + (widx & 7);                 // 0..63
  int nb = widx >> 3;                            // 0..17
  int m0 = mb * 128, n0 = nb * 128;
  int wm = (wave >> 1) * 64, wn = (wave & 1) * 64;
  floatx4 acc[4][4] = {};

  for (int kb = 0; kb < K; kb += 128) {
#pragma unroll
    for (int i = 0; i < 8; i++) {
      int op = wave * 8 + i;
      int srow = op * 4 + sr4;
      int sc = c16 ^ (srow & 15);
      load_lds16(A + (size_t)(m0 + srow) * K + kb + sc * 8, (char*)As + op * 1024);
    }
#pragma unroll
    for (int i = 0; i < 8; i++) {
      int op = wave * 8 + i;
      int srow = op * 4 + sr4;
      int sc = c16 ^ (srow & 15);
      load_lds16(Bt + (size_t)(n0 + srow) * K + kb + sc * 8, (char*)Bs + op * 1024);
    }
    __syncthreads();
#pragma unroll
    for (int ks = 0; ks < 4; ks++) {
      short8 af[4], bfr[4];
#pragma unroll
      for (int mt = 0; mt < 4; mt++)
        af[mt] = *(const short8*)(As + (wm + mt * 16 + l16) * 128 + ((ks * 4 + quad) ^ l16) * 8);
#pragma unroll
      for (int nt = 0; nt < 4; nt++)
        bfr[nt] = *(const short8*)(Bs + (wn + nt * 16 + l16) * 128 + ((ks * 4 + quad) ^ l16) * 8);
#pragma unroll
      for (int mt = 0; mt < 4; mt++)
#pragma unroll
        for (int nt = 0; nt < 4; nt++)
          acc[mt][nt] = __builtin_amdgcn_mfma_f32_16x16x32_bf16(af[mt], bfr[nt], acc[mt][nt], 0, 0, 0);
    }
    __syncthreads();
  }

  unsigned short* scr = LDSbuf + wave * 4608;  // per-wave scratch, row stride 72 ushorts
  if (n0 < 2 * DM_) {
    float qs = (n0 < DM_) ? 0.18033688011112042f : 1.0f;  // 0.125*log2(e) pre-scales Q
#pragma unroll
    for (int nt = 0; nt < 4; nt++) {
      float bv = bias[n0 + wn + nt * 16 + l16];
#pragma unroll
      for (int mt = 0; mt < 4; mt++)
#pragma unroll
        for (int r = 0; r < 4; r++)
          scr[(mt * 16 + quad * 4 + r) * 72 + nt * 16 + l16] = f2b((acc[mt][nt][r] + bv) * qs);
    }
#pragma unroll
    for (int it = 0; it < 8; it++) {
      int row = it * 8 + (lane >> 3);
      int ch = lane & 7;
      ushort8 w = *(const ushort8*)(scr + row * 72 + ch * 8);
      *(ushort8*)(Cout + (size_t)(m0 + wm + row) * N + n0 + wn + ch * 8) = w;
    }
  } else {
    int h = (n0 + wn - 2 * DM_) >> 6;
    int b = m0 >> 11;
    int s_base = (m0 & (S_ - 1)) + wm;
#pragma unroll
    for (int nt = 0; nt < 4; nt++) {
      float bv = bias[n0 + wn + nt * 16 + l16];
      ushort8 v0, v1;
#pragma unroll
      for (int j = 0; j < 8; j++) {
        v0[j] = f2b(acc[j & 3][nt][j >> 2] + bv);
        v1[j] = f2b(acc[j & 3][nt][2 + (j >> 2)] + bv);
      }
      *(ushort8*)(scr + (nt * 16 + l16) * 72 + quad * 16) = v0;
      *(ushort8*)(scr + (nt * 16 + l16) * 72 + quad * 16 + 8) = v1;
    }
#pragma unroll
    for (int it = 0; it < 8; it++) {
      int d = it * 8 + (lane >> 3);
      int ch = lane & 7;
      ushort8 w = *(const ushort8*)(scr + d * 72 + ch * 8);
      *(ushort8*)(Vt + ((size_t)(b * H_ + h) * 64 + d) * S_ + s_base + ch * 8) = w;
    }
  }
}

// ---------------- bf16 MFMA GEMM (64x128 tile, 4 blocks/CU): MLP GEMMs ----------------
template <int EPI>
__global__ __launch_bounds__(256, 4) void gemm64(
    const unsigned short* __restrict__ A,
    const unsigned short* __restrict__ Bt,
    const float* __restrict__ bias,
    const unsigned short* __restrict__ res,
    unsigned short* __restrict__ Cout,
    int M, int N, int K) {
  __shared__ __align__(16) unsigned short As[64 * 64];
  __shared__ __align__(16) unsigned short Bs[128 * 64];
  int tid = threadIdx.x;
  int wave = tid >> 6, lane = tid & 63;
  int quad = lane >> 4, l16 = lane & 15;
  int e = l16 & 7;
  int sr = lane >> 3;
  int sc = (lane & 7) ^ (sr & 7);
  int flat = blockIdx.x;              // 0..767
  int xcd = flat & 7, widx = flat >> 3;          // widx 0..95
  int mb = xcd * 16 + (widx & 15);               // 0..127
  int nb = widx >> 4;                            // 0..5
  int m0 = mb * 64, n0 = nb * 128;
  int wm = (wave >> 1) * 32, wn = (wave & 1) * 64;
  floatx4 acc[2][4] = {};

  for (int kb = 0; kb < K; kb += 64) {
#pragma unroll
    for (int i = 0; i < 2; i++) {
      int op = wave * 2 + i;  // 8 A ops
      load_lds16(A + (size_t)(m0 + op * 8 + sr) * K + kb + sc * 8, (char*)As + op * 1024);
    }
#pragma unroll
    for (int i = 0; i < 4; i++) {
      int op = wave * 4 + i;  // 16 B ops
      load_lds16(Bt + (size_t)(n0 + op * 8 + sr) * K + kb + sc * 8, (char*)Bs + op * 1024);
    }
    __syncthreads();
#pragma unroll
    for (int ks = 0; ks < 2; ks++) {
      short8 af[2], bfr[4];
#pragma unroll
      for (int mt = 0; mt < 2; mt++)
        af[mt] = *(const short8*)(As + (wm + mt * 16 + l16) * 64 + ((ks * 4 + quad) ^ e) * 8);
#pragma unroll
      for (int nt = 0; nt < 4; nt++)
        bfr[nt] = *(const short8*)(Bs + (wn + nt * 16 + l16) * 64 + ((ks * 4 + quad) ^ e) * 8);
#pragma unroll
      for (int mt = 0; mt < 2; mt++)
#pragma unroll
        for (int nt = 0; nt < 4; nt++)
          acc[mt][nt] = __builtin_amdgcn_mfma_f32_16x16x32_bf16(af[mt], bfr[nt], acc[mt][nt], 0, 0, 0);
    }
    __syncthreads();
  }
#pragma unroll
  for (int mt = 0; mt < 2; mt++) {
#pragma unroll
    for (int nt = 0; nt < 4; nt++) {
#pragma unroll
      for (int r = 0; r < 4; r++) {
        int row = m0 + wm + mt * 16 + quad * 4 + r;
        int col = n0 + wn + nt * 16 + l16;
        size_t idx = (size_t)row * N + col;
        float v = acc[mt][nt][r] + bias[col];
        if (EPI == 2) v = fmaxf(v, 0.0f);
        v += b2f(res[idx]);
        Cout[idx] = f2b(v);
      }
    }
  }
}

// ---------------- flash attention: av = softmax(Q K^T / 8) V ----------------
// R9 pipeline rotation (T15 mechanism, plain __syncthreads): per iteration,
//   [stageK(kt+1) | exp2/pack(kt)] -> barrier -> [PV(kt) INTERLEAVED with QK(kt+1)]
//   -> stageV(kt+1).
// PV(kt) (reads Vs[cur], Ps) and QK(kt+1) (reads Ks[cur^1], staged pre-barrier) are
// independent chains in ONE scheduling region -> ILP instead of the old serial
// QK->exp->pack->PV chain. Hazards: every cross-wave WAR pair is separated by a
// __syncthreads in both waves' program order (K-overwrite by barrier(kt-1)->(kt);
// V-overwrite: stageV(kt+2) only after barrier(kt+1) which follows all PV(kt)).
__global__ __launch_bounds__(256, 3) void attn(
    const unsigned short* __restrict__ qkv,
    const unsigned short* __restrict__ Vt,
    unsigned short* __restrict__ av) {
  int flat = blockIdx.x;                  // 0..767
  int widx = (flat & 7) * 96 + (flat >> 3);
  int qt = widx & 15;    // q-tile 0..15 (128 rows)
  int bh = widx >> 4;    // 0..47
  int b = bh / H_, h = bh % H_;
  int row0 = b * S_ + qt * 128;
  __shared__ __align__(16) unsigned short Ks[2][64 * 64];
  __shared__ __align__(16) unsigned short Vs[2][64 * 64];
  __shared__ __align__(16) unsigned short Ps[4][32 * 72];  // row stride 144B; doubles as Q staging
  int tid = threadIdx.x;
  int wave = tid >> 6, lane = tid & 63;
  int quad = lane >> 4, l16 = lane & 15;
  int e = l16 & 7;
  int sr = lane >> 3;
  int sc = (lane & 7) ^ (sr & 7);

  // stage this wave's 32 Q rows into its own Ps slab (row stride 128B, swizzled chunks)
#pragma unroll
  for (int i = 0; i < 4; i++) {
    load_lds16(qkv + (size_t)(row0 + wave * 32 + i * 8 + sr) * QKVN + h * HD_ + sc * 8,
               (char*)Ps[wave] + i * 1024);
  }
  const unsigned short* kp = qkv + (size_t)(b * S_ + wave * 16 + sr) * QKVN + DM_ + h * HD_ + sc * 8;
  const unsigned short* vp = Vt + ((size_t)bh * 64 + wave * 16 + sr) * S_ + sc * 8;
  auto stageK = [&](const unsigned short* kq, int buf) {
#pragma unroll
    for (int i = 0; i < 2; i++)
      load_lds16(kq + (size_t)i * 8 * QKVN, (char*)Ks[buf] + wave * 2048 + i * 1024);
  };
  auto stageV = [&](const unsigned short* vq, int buf) {
#pragma unroll
    for (int i = 0; i < 2; i++)
      load_lds16(vq + (size_t)i * 8 * S_, (char*)Vs[buf] + wave * 2048 + i * 1024);
  };
  stageK(kp, 0);
  stageV(vp, 0);

  floatx4 accO[2][4] = {};
  floatx4 accL[2] = {};
  short8 ones;
#pragma unroll
  for (int j = 0; j < 8; j++) ones[j] = (short)0x3F80;  // bf16 1.0
  __syncthreads();  // Q + K(0) + V(0) staged (drains vmcnt)

  // hoist Q fragments (before any P write; same-wave ordering)
  short8 qf[2][2];
#pragma unroll
  for (int mf = 0; mf < 2; mf++)
#pragma unroll
    for (int ks = 0; ks < 2; ks++)
      qf[mf][ks] = *(const short8*)(Ps[wave] + (mf * 16 + l16) * 64 + ((ks * 4 + quad) ^ e) * 8);

  // QK(0) from Ks[0]
  floatx4 sv[2][4] = {};
#pragma unroll
  for (int ks = 0; ks < 2; ks++)
#pragma unroll
    for (int nt = 0; nt < 4; nt++) {
      short8 kf = *(const short8*)(Ks[0] + (nt * 16 + l16) * 64 + ((ks * 4 + quad) ^ e) * 8);
#pragma unroll
      for (int mf = 0; mf < 2; mf++)
        sv[mf][nt] = __builtin_amdgcn_mfma_f32_16x16x32_bf16(qf[mf][ks], kf, sv[mf][nt], 0, 0, 0);
    }

  for (int kt = 0; kt < 32; kt++) {
    int cur = kt & 1;
    // issue K(kt+1) staging; latency covered by exp2/pack below (K is XCD-L2-resident)
    if (kt + 1 < 32) {
      kp += 64 * QKVN;
      stageK(kp, cur ^ 1);
    }
    // p = exp2(sv(kt)); pack 4 bf16 -> b64 write into this wave's Ps slab
#pragma unroll
    for (int mf = 0; mf < 2; mf++)
#pragma unroll
      for (int r = 0; r < 4; r++) {
        uint32_t u0 = fbits(__builtin_amdgcn_exp2f(sv[mf][0][r]));
        uint32_t u1 = fbits(__builtin_amdgcn_exp2f(sv[mf][1][r]));
        uint32_t u2 = fbits(__builtin_amdgcn_exp2f(sv[mf][2][r]));
        uint32_t u3 = fbits(__builtin_amdgcn_exp2f(sv[mf][3][r]));
        uint2 val;
        val.x = __builtin_amdgcn_perm(u1, u0, 0x07060302u);  // [u0.hi16, u1.hi16]
        val.y = __builtin_amdgcn_perm(u3, u2, 0x07060302u);  // [u2.hi16, u3.hi16]
        *(uint2*)(&Ps[wave][(mf * 16 + quad * 4 + r) * 72 + l16 * 4]) = val;
      }
    __syncthreads();  // drains K(kt+1) stage; all waves done with Ks/Vs[cur] reads of kt-1
    // PV(kt) interleaved with QK(kt+1): two independent chains, one region
    floatx4 nsv[2][4] = {};
    __builtin_amdgcn_s_setprio(1);
#pragma unroll
    for (int ks = 0; ks < 2; ks++) {
      short8 pf[2];
#pragma unroll
      for (int mf = 0; mf < 2; mf++) {
        pf[mf] = *(const short8*)(Ps[wave] + (mf * 16 + l16) * 72 + ks * 32 + quad * 8);
        accL[mf] = __builtin_amdgcn_mfma_f32_16x16x32_bf16(pf[mf], ones, accL[mf], 0, 0, 0);
      }
#pragma unroll
      for (int nt = 0; nt < 4; nt++) {
        short8 vf = *(const short8*)(Vs[cur] + (nt * 16 + l16) * 64 + ((ks * 4 + quad) ^ e) * 8);
#pragma unroll
        for (int mf = 0; mf < 2; mf++)
          accO[mf][nt] = __builtin_amdgcn_mfma_f32_16x16x32_bf16(pf[mf], vf, accO[mf][nt], 0, 0, 0);
      }
      if (kt + 1 < 32) {
#pragma unroll
        for (int nt = 0; nt < 4; nt++) {
          short8 kf = *(const short8*)(Ks[cur ^ 1] + (nt * 16 + l16) * 64 + ((ks * 4 + quad) ^ e) * 8);
#pragma unroll
          for (int mf = 0; mf < 2; mf++)
            nsv[mf][nt] = __builtin_amdgcn_mfma_f32_16x16x32_bf16(qf[mf][ks], kf, nsv[mf][nt], 0, 0, 0);
        }
      }
    }
    __builtin_amdgcn_s_setprio(0);
    // V(kt+1) staging after PV(kt): protected by barrier(kt+1) before PV(kt+1) reads it
    if (kt + 1 < 32) {
      vp += 64;
      stageV(vp, cur ^ 1);
    }
#pragma unroll
    for (int mf = 0; mf < 2; mf++)
#pragma unroll
      for (int nt = 0; nt < 4; nt++) sv[mf][nt] = nsv[mf][nt];
  }
#pragma unroll
  for (int mf = 0; mf < 2; mf++)
#pragma unroll
    for (int r = 0; r < 4; r++) {
      float inv = 1.0f / accL[mf][r];
      int row = row0 + wave * 32 + mf * 16 + quad * 4 + r;
#pragma unroll
      for (int nt = 0; nt < 4; nt++)
        av[(size_t)row * DM_ + h * HD_ + nt * 16 + l16] = f2b(accO[mf][nt][r] * inv);
    }
}

// ---------------- row norm: (x-mean)/std * scale + bias (bf16 input) ----------------
// WB=1: write bf16 only. WB=0: write f32 only (final output).
template <int WB>
__global__ __launch_bounds__(256) void normk(
    const unsigned short* __restrict__ X, const float* __restrict__ scale,
    const float* __restrict__ bias, float* __restrict__ Y,
    unsigned short* __restrict__ Ybf) {
  int row = blockIdx.x;
  const unsigned short* x = X + (size_t)row * DM_;
  int tid = threadIdx.x;
  int wave = tid >> 6, lane = tid & 63;
  float v[3];
#pragma unroll
  for (int i = 0; i < 3; i++) v[i] = b2f(x[tid + i * 256]);
  float s = v[0] + v[1] + v[2];
#pragma unroll
  for (int o = 32; o > 0; o >>= 1) s += __shfl_xor(s, o);
  __shared__ float red[4];
  if (lane == 0) red[wave] = s;
  __syncthreads();
  float mean = (red[0] + red[1] + red[2] + red[3]) * (1.0f / DM_);
  float ss = 0.0f;
#pragma unroll
  for (int i = 0; i < 3; i++) { v[i] -= mean; ss += v[i] * v[i]; }
#pragma unroll
  for (int o = 32; o > 0; o >>= 1) ss += __shfl_xor(ss, o);
  __syncthreads();
  if (lane == 0) red[wave] = ss;
  __syncthreads();
  float var = (red[0] + red[1] + red[2] + red[3]) * (1.0f / DM_);
  float rstd = rsqrtf(var);
  float sg = scale[0], bg = bias[0];
#pragma unroll
  for (int i = 0; i < 3; i++) {
    float y = v[i] * rstd * sg + bg;
    if (WB) Ybf[(size_t)row * DM_ + tid + i * 256] = f2b(y);
    else    Y[(size_t)row * DM_ + tid + i * 256] = y;
  }
}

extern "C" void kernel_launch(void* const* d_in, const int* in_sizes, int n_in,
                              void* d_out, int out_size, void* d_ws, size_t ws_size,
                              hipStream_t stream) {
  const float* base = (const float*)d_in[0];
  const float* Wqkv = (const float*)d_in[1];
  const float* bqkv = (const float*)d_in[2];
  const float* W1 = (const float*)d_in[3];
  const float* b1 = (const float*)d_in[4];
  const float* W2 = (const float*)d_in[5];
  const float* b2 = (const float*)d_in[6];
  const float* n1s = (const float*)d_in[7];
  const float* n1b = (const float*)d_in[8];
  const float* n2s = (const float*)d_in[9];
  const float* n2b = (const float*)d_in[10];
  float* out = (float*)d_out;

  char* ws = (char*)d_ws;
  size_t off = 0;
  auto alloc = [&](size_t bytes) {
    char* p = ws + off;
    off = (off + bytes + 255) & ~(size_t)255;
    return p;
  };
  unsigned short* base_bf = (unsigned short*)alloc((size_t)ROWS * DM_ * 2);
  unsigned short* Wqkvt = (unsigned short*)alloc((size_t)QKVN * DM_ * 2);
  unsigned short* W1t = (unsigned short*)alloc((size_t)DM_ * DM_ * 2);
  unsigned short* W2t = (unsigned short*)alloc((size_t)DM_ * DM_ * 2);
  unsigned short* qkvb = (unsigned short*)alloc((size_t)ROWS * QKVN * 2);
  unsigned short* Vtb = (unsigned short*)alloc((size_t)B_ * H_ * HD_ * S_ * 2);
  unsigned short* avb = (unsigned short*)alloc((size_t)ROWS * DM_ * 2);
  unsigned short* t1b = (unsigned short*)alloc((size_t)ROWS * DM_ * 2);   // reused for t2
  unsigned short* hbf = (unsigned short*)alloc((size_t)ROWS * DM_ * 2);

  prep<<<CVT_B + WQ_B + 2 * W1_B, 256, 0, stream>>>(
      base, base_bf, Wqkv, Wqkvt, W1, W1t, W2, W2t);
  gemm_qkv<<<dim3((QKVN / 128) * (ROWS / 128)), 256, 0, stream>>>(
      base_bf, Wqkvt, bqkv, qkvb, Vtb, ROWS, QKVN, DM_);
  attn<<<dim3((S_ / 128) * (B_ * H_)), 256, 0, stream>>>(qkvb, Vtb, avb);  // 768 blocks
  gemm64<1><<<dim3((DM_ / 128) * (ROWS / 64)), 256, 0, stream>>>(
      avb, W1t, b1, base_bf, t1b, ROWS, DM_, DM_);
  normk<1><<<ROWS, 256, 0, stream>>>(t1b, n1s, n1b, nullptr, hbf);
  gemm64<2><<<dim3((DM_ / 128) * (ROWS / 64)), 256, 0, stream>>>(
      hbf, W2t, b2, hbf, t1b, ROWS, DM_, DM_);
  normk<0><<<ROWS, 256, 0, stream>>>(t1b, n2s, n2b, out, nullptr);
}